// Round 8
// baseline (423.544 us; speedup 1.0000x reference)
//
#include <hip/hip_runtime.h>
#include <cmath>

#define FACTOR 0.08838834764831845f

typedef short s16x8 __attribute__((ext_vector_type(8)));
typedef float f32x4 __attribute__((ext_vector_type(4)));

__device__ __forceinline__ unsigned short f2bf(float x) {
  unsigned int u = __float_as_uint(x);
  u += 0x7FFFu + ((u >> 16) & 1u);
  return (unsigned short)(u >> 16);
}

__device__ __forceinline__ s16x8 pack8(float4 a, float4 b) {
  s16x8 r;
  r[0] = (short)f2bf(a.x); r[1] = (short)f2bf(a.y);
  r[2] = (short)f2bf(a.z); r[3] = (short)f2bf(a.w);
  r[4] = (short)f2bf(b.x); r[5] = (short)f2bf(b.y);
  r[6] = (short)f2bf(b.z); r[7] = (short)f2bf(b.w);
  return r;
}

// ---------------------------------------------------------------------------
// MFMA GEMM: C = A[M,K] @ B[N,K]^T (+bias). Raw-barrier K-loop, unroll 1
// (prevents full unroll -> I$ thrash + prefetch live-range spills).
// mode 0: f32 C | mode 3: bf16 C | mode 4/5: Vt scatters (5 = fused V transpose)
// ---------------------------------------------------------------------------
__global__ __launch_bounds__(256) void gemm_mfma(
    const float* __restrict__ A, const float* __restrict__ B,
    const float* __restrict__ bias, void* __restrict__ C,
    int M, int N, int K, int mode)
{
  __shared__ unsigned short As[128 * 72];
  __shared__ unsigned short Bs[128 * 72];

  const int tid = threadIdx.x;
  const int w = tid >> 6, lane = tid & 63;
  const int l16 = lane & 15, lg = lane >> 4;
  const int wm = w >> 1, wn = w & 1;
  const int m0 = blockIdx.x * 128;
  const int n0 = blockIdx.y * 128;

  const int sr = tid >> 3;
  const int sc = (tid & 7) * 8;

  float4 ar[4][2], br[4][2];

  auto issue = [&](int k0) {
#pragma unroll
    for (int i = 0; i < 4; ++i) {
      const int rr = i * 32 + sr;
      const float* ap = A + (size_t)(m0 + rr) * K + k0 + sc;
      ar[i][0] = *(const float4*)ap;
      ar[i][1] = *(const float4*)(ap + 4);
      const float* bp;
      if (mode == 5) {
        const int t = n0 + rr;
        const int q3 = t >> 10, n = t & 1023;
        const int bb = q3 / 3, cd = q3 - 3 * bb;
        bp = B + (((size_t)(bb * 1024 + n)) * 3 + cd) * 512 + k0 + sc;
      } else {
        bp = B + (size_t)(n0 + rr) * K + k0 + sc;
      }
      br[i][0] = *(const float4*)bp;
      br[i][1] = *(const float4*)(bp + 4);
    }
  };

  f32x4 acc[4][4];
#pragma unroll
  for (int mt = 0; mt < 4; ++mt)
#pragma unroll
    for (int nt = 0; nt < 4; ++nt)
#pragma unroll
      for (int r = 0; r < 4; ++r) acc[mt][nt][r] = 0.f;

  issue(0);

#pragma unroll 1
  for (int k0 = 0; k0 < K; k0 += 64) {
    __builtin_amdgcn_s_barrier();          // readers of prior slab done
#pragma unroll
    for (int i = 0; i < 4; ++i) {          // compiler waits exact vmcnt here
      const int rr = i * 32 + sr;
      *(s16x8*)&As[rr * 72 + sc] = pack8(ar[i][0], ar[i][1]);
      *(s16x8*)&Bs[rr * 72 + sc] = pack8(br[i][0], br[i][1]);
    }
    asm volatile("s_waitcnt lgkmcnt(0)" ::: "memory");
    __builtin_amdgcn_s_barrier();          // slab visible to all waves
    if (k0 + 64 < K) issue(k0 + 64);       // stays in flight across next barrier

#pragma unroll
    for (int ks = 0; ks < 2; ++ks) {
      s16x8 af[4], bf[4];
#pragma unroll
      for (int mt = 0; mt < 4; ++mt)
        af[mt] = *(const s16x8*)&As[(wm * 64 + mt * 16 + l16) * 72 + ks * 32 + lg * 8];
#pragma unroll
      for (int nt = 0; nt < 4; ++nt)
        bf[nt] = *(const s16x8*)&Bs[(wn * 64 + nt * 16 + l16) * 72 + ks * 32 + lg * 8];
#pragma unroll
      for (int mt = 0; mt < 4; ++mt)
#pragma unroll
        for (int nt = 0; nt < 4; ++nt)
          acc[mt][nt] = __builtin_amdgcn_mfma_f32_16x16x32_bf16(af[mt], bf[nt], acc[mt][nt], 0, 0, 0);
    }
  }

  const int rbase = m0 + wm * 64;
  const int cbase = n0 + wn * 64;

  if (mode == 0 || mode == 3) {
#pragma unroll
    for (int nt = 0; nt < 4; ++nt) {
      const int c = cbase + nt * 16 + l16;
      const float bb = bias ? bias[c] : 0.f;
#pragma unroll
      for (int mt = 0; mt < 4; ++mt) {
#pragma unroll
        for (int r = 0; r < 4; ++r) {
          const int row = rbase + mt * 16 + lg * 4 + r;
          const float v = acc[mt][nt][r] + bb;
          if (mode == 0) ((float*)C)[(size_t)row * N + c] = v;
          else           ((unsigned short*)C)[(size_t)row * N + c] = f2bf(v);
        }
      }
    }
  } else {
    unsigned short* Cb = (unsigned short*)C;
#pragma unroll
    for (int mt = 0; mt < 4; ++mt) {
#pragma unroll
      for (int r = 0; r < 4; ++r) {
        const int ch = rbase + mt * 16 + lg * 4 + r;
        const float bb = bias ? bias[ch] : 0.f;
        const int h = ch >> 5, dq = ch & 31;
#pragma unroll
        for (int nt = 0; nt < 4; ++nt) {
          const int t = cbase + nt * 16 + l16;
          size_t off;
          if (mode == 4) {
            const int b = t >> 10, n = t & 1023;
            off = (((size_t)(b * 16 + h)) * 128 + dq) * 1024 + n;
          } else {
            const int q3 = t >> 10, n = t & 1023;
            const int b = q3 / 3, cd = q3 - 3 * b;
            off = (((size_t)(b * 16 + h)) * 128 + 32 + cd * 32 + dq) * 1024 + n;
          }
          Cb[off] = f2bf(acc[mt][nt][r] + bb);
        }
      }
    }
  }
}

// ---------------------------------------------------------------------------
// MFMA flash attention, raw-barrier pipeline, unroll 1 on the KV-tile loop.
// ---------------------------------------------------------------------------
#define KP 136
#define VP 72
#define PP 72

__global__ __launch_bounds__(256, 3) void attn_mfma(
    const unsigned short* __restrict__ Qg, const unsigned short* __restrict__ Kg,
    const unsigned short* __restrict__ Vtg, const float* __restrict__ rbf,
    const float* __restrict__ Dm, const int* __restrict__ msk,
    float* __restrict__ Hres, float* __restrict__ Vres)
{
  __shared__ unsigned short KsL[64 * KP];
  __shared__ unsigned short VtL[128 * VP];
  __shared__ unsigned short PsL[64 * PP];

  const int tid  = threadIdx.x;
  const int w    = tid >> 6;
  const int lane = tid & 63;
  const int l16  = lane & 15;
  const int lg   = lane >> 4;

  const int bh = blockIdx.y;
  const int b  = bh >> 4;
  const int h  = bh & 15;
  const int r0 = blockIdx.x * 64;
  const int q0 = r0 + w * 16;

  const int kr = tid >> 4,  kc = (tid & 15) * 8;
  const int vd = tid >> 3,  vc = (tid & 7) * 8;
  const unsigned short* KgB  = Kg  + ((size_t)(b * 1024) + kr) * 2048 + h * 128 + kc;
  const unsigned short* VtgB = Vtg + ((size_t)bh * 128 + vd) * 1024 + vc;

  s16x8 qf[4];
  {
    const unsigned short* qp = Qg + ((size_t)(b * 1024 + q0 + l16)) * 2048 + h * 128 + lg * 8;
#pragma unroll
    for (int ks = 0; ks < 4; ++ks) qf[ks] = *(const s16x8*)(qp + ks * 32);
  }

  float m_run[4], l_run[4];
  f32x4 acc[8];
#pragma unroll
  for (int r = 0; r < 4; ++r) { m_run[r] = -INFINITY; l_run[r] = 0.f; }
#pragma unroll
  for (int vt = 0; vt < 8; ++vt)
#pragma unroll
    for (int r = 0; r < 4; ++r) acc[vt][r] = 0.f;

  size_t rb_base[4], db_base[4];
#pragma unroll
  for (int r = 0; r < 4; ++r) {
    const int qg = q0 + lg * 4 + r;
    rb_base[r] = ((size_t)bh * 1024 + qg) * 1024;
    db_base[r] = ((size_t)b * 1024 + qg) * 1024;
  }
  const int mbase = b * 1024;

  // ---- prologue: K/V(0), bias(0) ----
  uint4 kst[4], vst[4];
#pragma unroll
  for (int i = 0; i < 4; ++i) {
    kst[i] = *(const uint4*)(KgB + (size_t)(i * 16) * 2048);
    vst[i] = *(const uint4*)(VtgB + (size_t)(i * 32) * 1024);
  }
  float rbv[4][4], dbv[4][4];
  int mkv[4];
#pragma unroll
  for (int mt = 0; mt < 4; ++mt) {
    const int m = mt * 16 + l16;
    mkv[mt] = msk[mbase + m];
#pragma unroll
    for (int r = 0; r < 4; ++r) {
      rbv[mt][r] = rbf[rb_base[r] + m];
      dbv[mt][r] = Dm[db_base[r] + m];
    }
  }

#pragma unroll 1
  for (int m0 = 0; m0 < 1024; m0 += 64) {
    __builtin_amdgcn_s_barrier();          // barA: prior tile's LDS reads done
#pragma unroll
    for (int i = 0; i < 4; ++i) {          // compiler waits exact vmcnt(kst/vst)
      *(uint4*)&KsL[(kr + i * 16) * KP + kc] = kst[i];
      *(uint4*)&VtL[(vd + i * 32) * VP + vc] = vst[i];
    }
    asm volatile("s_waitcnt lgkmcnt(0)" ::: "memory");
    __builtin_amdgcn_s_barrier();          // barB: tile m0 visible

    // ---- issue NEXT tile's K/V (in flight through this tile) ----
    if (m0 < 960) {
      const size_t koff = (size_t)(m0 + 64) * 2048;
      const size_t voff = (size_t)(m0 + 64);
#pragma unroll
      for (int i = 0; i < 4; ++i) {
        kst[i] = *(const uint4*)(KgB + koff + (size_t)(i * 16) * 2048);
        vst[i] = *(const uint4*)(VtgB + voff + (size_t)(i * 32) * 1024);
      }
    }

    // ---- QK scores ----
    __builtin_amdgcn_s_setprio(1);
    f32x4 sf[4];
#pragma unroll
    for (int mt = 0; mt < 4; ++mt) {
      f32x4 s;
#pragma unroll
      for (int r = 0; r < 4; ++r) s[r] = 0.f;
#pragma unroll
      for (int ks = 0; ks < 4; ++ks) {
        const s16x8 kf = *(const s16x8*)&KsL[(mt * 16 + l16) * KP + ks * 32 + lg * 8];
        s = __builtin_amdgcn_mfma_f32_16x16x32_bf16(qf[ks], kf, s, 0, 0, 0);
      }
      sf[mt] = s;
    }
    __builtin_amdgcn_s_setprio(0);

    // ---- consume bias(t) ----
    float sv[4][4];
#pragma unroll
    for (int mt = 0; mt < 4; ++mt) {
      const bool on = mkv[mt] != 0;
#pragma unroll
      for (int r = 0; r < 4; ++r) {
        const float x = fmaf(sf[mt][r], FACTOR, rbv[mt][r] + dbv[mt][r]);
        sv[mt][r] = on ? x : -INFINITY;
      }
    }

    // ---- issue bias(t+1) ----
    if (m0 < 960) {
#pragma unroll
      for (int mt = 0; mt < 4; ++mt) {
        const int m = m0 + 64 + mt * 16 + l16;
        mkv[mt] = msk[mbase + m];
#pragma unroll
        for (int r = 0; r < 4; ++r) {
          rbv[mt][r] = rbf[rb_base[r] + m];
          dbv[mt][r] = Dm[db_base[r] + m];
        }
      }
    }

    // ---- online softmax ----
    float psv[4][4];
#pragma unroll
    for (int r = 0; r < 4; ++r) {
      float tm = fmaxf(fmaxf(sv[0][r], sv[1][r]), fmaxf(sv[2][r], sv[3][r]));
      tm = fmaxf(tm, __shfl_xor(tm, 1));
      tm = fmaxf(tm, __shfl_xor(tm, 2));
      tm = fmaxf(tm, __shfl_xor(tm, 4));
      tm = fmaxf(tm, __shfl_xor(tm, 8));
      const float mn = fmaxf(m_run[r], tm);
      const float sc = (mn == m_run[r]) ? 1.f : __expf(m_run[r] - mn);
      m_run[r] = mn;
      float rs = 0.f;
#pragma unroll
      for (int mt = 0; mt < 4; ++mt) {
        const float s = sv[mt][r];
        const float p = (s == -INFINITY) ? 0.f : __expf(s - mn);
        psv[mt][r] = p;
        rs += p;
      }
      rs += __shfl_xor(rs, 1);
      rs += __shfl_xor(rs, 2);
      rs += __shfl_xor(rs, 4);
      rs += __shfl_xor(rs, 8);
      l_run[r] = l_run[r] * sc + rs;
#pragma unroll
      for (int vt = 0; vt < 8; ++vt) acc[vt][r] *= sc;
    }

    // ---- P -> LDS (per-wave region), then PV ----
#pragma unroll
    for (int mt = 0; mt < 4; ++mt)
#pragma unroll
      for (int r = 0; r < 4; ++r)
        PsL[(w * 16 + lg * 4 + r) * PP + mt * 16 + l16] = f2bf(psv[mt][r]);
    asm volatile("s_waitcnt lgkmcnt(0)" ::: "memory");
    __builtin_amdgcn_sched_barrier(0);

    s16x8 pf[2];
#pragma unroll
    for (int ks = 0; ks < 2; ++ks)
      pf[ks] = *(const s16x8*)&PsL[(w * 16 + l16) * PP + ks * 32 + lg * 8];
    __builtin_amdgcn_s_setprio(1);
#pragma unroll
    for (int vt = 0; vt < 8; ++vt) {
#pragma unroll
      for (int ks = 0; ks < 2; ++ks) {
        const s16x8 vf = *(const s16x8*)&VtL[(vt * 16 + l16) * VP + ks * 32 + lg * 8];
        acc[vt] = __builtin_amdgcn_mfma_f32_16x16x32_bf16(pf[ks], vf, acc[vt], 0, 0, 0);
      }
    }
    __builtin_amdgcn_s_setprio(0);
  }

  float inv[4];
#pragma unroll
  for (int r = 0; r < 4; ++r) inv[r] = (l_run[r] > 0.f) ? 1.f / l_run[r] : 0.f;

#pragma unroll
  for (int vt = 0; vt < 8; ++vt) {
    const int vdim = vt * 16 + l16;
#pragma unroll
    for (int r = 0; r < 4; ++r) {
      const int q = q0 + lg * 4 + r;
      const float o = acc[vt][r] * inv[r];
      if (vdim < 32) {
        Hres[((size_t)(b * 1024 + q)) * 512 + h * 32 + vdim] = o;
      } else {
        const int ix = vdim - 32, cd = ix >> 5, kq = ix & 31;
        Vres[(((size_t)(b * 1024 + q)) * 3 + cd) * 512 + h * 32 + kq] = o;
      }
    }
  }
}

// ---------------------------------------------------------------------------
extern "C" void kernel_launch(void* const* d_in, const int* in_sizes, int n_in,
                              void* d_out, int out_size, void* d_ws, size_t ws_size,
                              hipStream_t stream)
{
  const float* Hp  = (const float*)d_in[0];
  const float* Vp  = (const float*)d_in[1];
  const float* Db  = (const float*)d_in[2];
  const float* rbf = (const float*)d_in[3];
  const int*   Hm  = (const int*)d_in[4];
  const float* Wq  = (const float*)d_in[5];
  const float* bq  = (const float*)d_in[6];
  const float* Wk  = (const float*)d_in[7];
  const float* bk  = (const float*)d_in[8];
  const float* Wv  = (const float*)d_in[9];
  const float* bv  = (const float*)d_in[10];
  const float* Wvv = (const float*)d_in[11];
  const float* Wo  = (const float*)d_in[12];
  const float* bo  = (const float*)d_in[13];
  const float* Wvo = (const float*)d_in[14];
  float* out = (float*)d_out;

  // ws (bytes): Qb 16M | Kb 16M | Vt 16M | Hres 8M | Vres 24M = 80MB
  if (ws_size < (size_t)83886080) return;
  unsigned short* Qb = (unsigned short*)d_ws;
  unsigned short* Kb = Qb + 8388608;
  unsigned short* Vt = Kb + 8388608;
  float* Hres = (float*)(Vt + 8388608);
  float* Vres = Hres + 2097152;

  const dim3 blk(256);

  gemm_mfma<<<dim3(32, 16), blk, 0, stream>>>(Hp, Wq, bq, Qb, 4096, 2048, 512, 3);
  gemm_mfma<<<dim3(32, 16), blk, 0, stream>>>(Hp, Wk, bk, Kb, 4096, 2048, 512, 3);
  gemm_mfma<<<dim3(4, 32),  blk, 0, stream>>>(Wv, Hp, bv, Vt, 512, 4096, 512, 4);
  gemm_mfma<<<dim3(4, 96),  blk, 0, stream>>>(Wvv, Vp, nullptr, Vt, 512, 12288, 512, 5);

  attn_mfma<<<dim3(16, 64), blk, 0, stream>>>(Qb, Kb, Vt, rbf, Db, Hm, Hres, Vres);

  gemm_mfma<<<dim3(32, 4), blk, 0, stream>>>(Hres, Wo, bo, out, 4096, 512, 512, 0);
  gemm_mfma<<<dim3(96, 4), blk, 0, stream>>>(Vres, Wvo, nullptr, out + 2097152, 12288, 512, 512, 0);
}

// Round 9
// 407.741 us; speedup vs baseline: 1.0388x; 1.0388x over previous
//
#include <hip/hip_runtime.h>
#include <cmath>

#define FACTOR 0.08838834764831845f

typedef short s16x8 __attribute__((ext_vector_type(8)));
typedef float f32x4 __attribute__((ext_vector_type(4)));

// Pin preceding loads: a load may not sink past a memory clobber, and
// sched_barrier(0) stops MIR-level motion too (rule #18-adjacent).
#define KEEP_LOADS() do { asm volatile("" ::: "memory"); __builtin_amdgcn_sched_barrier(0); } while (0)

__device__ __forceinline__ unsigned short f2bf(float x) {
  unsigned int u = __float_as_uint(x);
  u += 0x7FFFu + ((u >> 16) & 1u);
  return (unsigned short)(u >> 16);
}

__device__ __forceinline__ s16x8 pack8(float4 a, float4 b) {
  s16x8 r;
  r[0] = (short)f2bf(a.x); r[1] = (short)f2bf(a.y);
  r[2] = (short)f2bf(a.z); r[3] = (short)f2bf(a.w);
  r[4] = (short)f2bf(b.x); r[5] = (short)f2bf(b.y);
  r[6] = (short)f2bf(b.z); r[7] = (short)f2bf(b.w);
  return r;
}

// ---------------------------------------------------------------------------
// MFMA GEMM: C = A[M,K] @ B[N,K]^T (+bias). Raw-barrier K-loop; prefetch
// pinned against sinking via KEEP_LOADS.
// mode 0: f32 C | mode 3: bf16 C | mode 4/5: Vt scatters (5 = fused V transpose)
// ---------------------------------------------------------------------------
__global__ __launch_bounds__(256) void gemm_mfma(
    const float* __restrict__ A, const float* __restrict__ B,
    const float* __restrict__ bias, void* __restrict__ C,
    int M, int N, int K, int mode)
{
  __shared__ unsigned short As[128 * 72];
  __shared__ unsigned short Bs[128 * 72];

  const int tid = threadIdx.x;
  const int w = tid >> 6, lane = tid & 63;
  const int l16 = lane & 15, lg = lane >> 4;
  const int wm = w >> 1, wn = w & 1;
  const int m0 = blockIdx.x * 128;
  const int n0 = blockIdx.y * 128;

  const int sr = tid >> 3;
  const int sc = (tid & 7) * 8;

  float4 ar[4][2], br[4][2];

  auto issue = [&](int k0) {
#pragma unroll
    for (int i = 0; i < 4; ++i) {
      const int rr = i * 32 + sr;
      const float* ap = A + (size_t)(m0 + rr) * K + k0 + sc;
      ar[i][0] = *(const float4*)ap;
      ar[i][1] = *(const float4*)(ap + 4);
      const float* bp;
      if (mode == 5) {
        const int t = n0 + rr;
        const int q3 = t >> 10, n = t & 1023;
        const int bb = q3 / 3, cd = q3 - 3 * bb;
        bp = B + (((size_t)(bb * 1024 + n)) * 3 + cd) * 512 + k0 + sc;
      } else {
        bp = B + (size_t)(n0 + rr) * K + k0 + sc;
      }
      br[i][0] = *(const float4*)bp;
      br[i][1] = *(const float4*)(bp + 4);
    }
  };

  f32x4 acc[4][4];
#pragma unroll
  for (int mt = 0; mt < 4; ++mt)
#pragma unroll
    for (int nt = 0; nt < 4; ++nt)
#pragma unroll
      for (int r = 0; r < 4; ++r) acc[mt][nt][r] = 0.f;

  issue(0);

#pragma unroll 1
  for (int k0 = 0; k0 < K; k0 += 64) {
    __builtin_amdgcn_s_barrier();          // readers of prior slab done
#pragma unroll
    for (int i = 0; i < 4; ++i) {          // compiler waits exact vmcnt here
      const int rr = i * 32 + sr;
      *(s16x8*)&As[rr * 72 + sc] = pack8(ar[i][0], ar[i][1]);
      *(s16x8*)&Bs[rr * 72 + sc] = pack8(br[i][0], br[i][1]);
    }
    asm volatile("s_waitcnt lgkmcnt(0)" ::: "memory");
    __builtin_amdgcn_s_barrier();          // slab visible to all waves
    if (k0 + 64 < K) issue(k0 + 64);       // stays in flight across next barrier
    KEEP_LOADS();

#pragma unroll
    for (int ks = 0; ks < 2; ++ks) {
      s16x8 af[4], bf[4];
#pragma unroll
      for (int mt = 0; mt < 4; ++mt)
        af[mt] = *(const s16x8*)&As[(wm * 64 + mt * 16 + l16) * 72 + ks * 32 + lg * 8];
#pragma unroll
      for (int nt = 0; nt < 4; ++nt)
        bf[nt] = *(const s16x8*)&Bs[(wn * 64 + nt * 16 + l16) * 72 + ks * 32 + lg * 8];
#pragma unroll
      for (int mt = 0; mt < 4; ++mt)
#pragma unroll
        for (int nt = 0; nt < 4; ++nt)
          acc[mt][nt] = __builtin_amdgcn_mfma_f32_16x16x32_bf16(af[mt], bf[nt], acc[mt][nt], 0, 0, 0);
    }
  }

  const int rbase = m0 + wm * 64;
  const int cbase = n0 + wn * 64;

  if (mode == 0 || mode == 3) {
#pragma unroll
    for (int nt = 0; nt < 4; ++nt) {
      const int c = cbase + nt * 16 + l16;
      const float bb = bias ? bias[c] : 0.f;
#pragma unroll
      for (int mt = 0; mt < 4; ++mt) {
#pragma unroll
        for (int r = 0; r < 4; ++r) {
          const int row = rbase + mt * 16 + lg * 4 + r;
          const float v = acc[mt][nt][r] + bb;
          if (mode == 0) ((float*)C)[(size_t)row * N + c] = v;
          else           ((unsigned short*)C)[(size_t)row * N + c] = f2bf(v);
        }
      }
    }
  } else {
    unsigned short* Cb = (unsigned short*)C;
#pragma unroll
    for (int mt = 0; mt < 4; ++mt) {
#pragma unroll
      for (int r = 0; r < 4; ++r) {
        const int ch = rbase + mt * 16 + lg * 4 + r;
        const float bb = bias ? bias[ch] : 0.f;
        const int h = ch >> 5, dq = ch & 31;
#pragma unroll
        for (int nt = 0; nt < 4; ++nt) {
          const int t = cbase + nt * 16 + l16;
          size_t off;
          if (mode == 4) {
            const int b = t >> 10, n = t & 1023;
            off = (((size_t)(b * 16 + h)) * 128 + dq) * 1024 + n;
          } else {
            const int q3 = t >> 10, n = t & 1023;
            const int b = q3 / 3, cd = q3 - 3 * b;
            off = (((size_t)(b * 16 + h)) * 128 + 32 + cd * 32 + dq) * 1024 + n;
          }
          Cb[off] = f2bf(acc[mt][nt][r] + bb);
        }
      }
    }
  }
}

// ---------------------------------------------------------------------------
// MFMA flash attention, raw-barrier pipeline; prefetches pinned in registers
// (KEEP_LOADS stops the compiler's load-sinking that serialized R5-R8).
// ---------------------------------------------------------------------------
#define KP 136
#define VP 72
#define PP 72

__global__ __launch_bounds__(256, 2) void attn_mfma(
    const unsigned short* __restrict__ Qg, const unsigned short* __restrict__ Kg,
    const unsigned short* __restrict__ Vtg, const float* __restrict__ rbf,
    const float* __restrict__ Dm, const int* __restrict__ msk,
    float* __restrict__ Hres, float* __restrict__ Vres)
{
  __shared__ unsigned short KsL[64 * KP];
  __shared__ unsigned short VtL[128 * VP];
  __shared__ unsigned short PsL[64 * PP];

  const int tid  = threadIdx.x;
  const int w    = tid >> 6;
  const int lane = tid & 63;
  const int l16  = lane & 15;
  const int lg   = lane >> 4;

  const int bh = blockIdx.y;
  const int b  = bh >> 4;
  const int h  = bh & 15;
  const int r0 = blockIdx.x * 64;
  const int q0 = r0 + w * 16;

  const int kr = tid >> 4,  kc = (tid & 15) * 8;
  const int vd = tid >> 3,  vc = (tid & 7) * 8;
  const unsigned short* KgB  = Kg  + ((size_t)(b * 1024) + kr) * 2048 + h * 128 + kc;
  const unsigned short* VtgB = Vtg + ((size_t)bh * 128 + vd) * 1024 + vc;

  s16x8 qf[4];
  {
    const unsigned short* qp = Qg + ((size_t)(b * 1024 + q0 + l16)) * 2048 + h * 128 + lg * 8;
#pragma unroll
    for (int ks = 0; ks < 4; ++ks) qf[ks] = *(const s16x8*)(qp + ks * 32);
  }

  float m_run[4], l_run[4];
  f32x4 acc[8];
#pragma unroll
  for (int r = 0; r < 4; ++r) { m_run[r] = -INFINITY; l_run[r] = 0.f; }
#pragma unroll
  for (int vt = 0; vt < 8; ++vt)
#pragma unroll
    for (int r = 0; r < 4; ++r) acc[vt][r] = 0.f;

  size_t rb_base[4], db_base[4];
#pragma unroll
  for (int r = 0; r < 4; ++r) {
    const int qg = q0 + lg * 4 + r;
    rb_base[r] = ((size_t)bh * 1024 + qg) * 1024;
    db_base[r] = ((size_t)b * 1024 + qg) * 1024;
  }
  const int mbase = b * 1024;

  // ---- prologue: K/V(0), bias(0) ----
  uint4 kst[4], vst[4];
#pragma unroll
  for (int i = 0; i < 4; ++i) {
    kst[i] = *(const uint4*)(KgB + (size_t)(i * 16) * 2048);
    vst[i] = *(const uint4*)(VtgB + (size_t)(i * 32) * 1024);
  }
  float rbv[4][4], dbv[4][4];
  int mkv[4];
#pragma unroll
  for (int mt = 0; mt < 4; ++mt) {
    const int m = mt * 16 + l16;
    mkv[mt] = msk[mbase + m];
#pragma unroll
    for (int r = 0; r < 4; ++r) {
      rbv[mt][r] = rbf[rb_base[r] + m];
      dbv[mt][r] = Dm[db_base[r] + m];
    }
  }

#pragma unroll 1
  for (int m0 = 0; m0 < 1024; m0 += 64) {
    __builtin_amdgcn_s_barrier();          // barA: prior tile's LDS reads done
#pragma unroll
    for (int i = 0; i < 4; ++i) {          // compiler waits exact vmcnt(kst/vst)
      *(uint4*)&KsL[(kr + i * 16) * KP + kc] = kst[i];
      *(uint4*)&VtL[(vd + i * 32) * VP + vc] = vst[i];
    }
    asm volatile("s_waitcnt lgkmcnt(0)" ::: "memory");
    __builtin_amdgcn_s_barrier();          // barB: tile m0 visible

    // ---- issue NEXT tile's K/V (pinned in flight through this tile) ----
    if (m0 < 960) {
      const size_t koff = (size_t)(m0 + 64) * 2048;
      const size_t voff = (size_t)(m0 + 64);
#pragma unroll
      for (int i = 0; i < 4; ++i) {
        kst[i] = *(const uint4*)(KgB + koff + (size_t)(i * 16) * 2048);
        vst[i] = *(const uint4*)(VtgB + voff + (size_t)(i * 32) * 1024);
      }
    }
    KEEP_LOADS();

    // ---- QK scores ----
    __builtin_amdgcn_s_setprio(1);
    f32x4 sf[4];
#pragma unroll
    for (int mt = 0; mt < 4; ++mt) {
      f32x4 s;
#pragma unroll
      for (int r = 0; r < 4; ++r) s[r] = 0.f;
#pragma unroll
      for (int ks = 0; ks < 4; ++ks) {
        const s16x8 kf = *(const s16x8*)&KsL[(mt * 16 + l16) * KP + ks * 32 + lg * 8];
        s = __builtin_amdgcn_mfma_f32_16x16x32_bf16(qf[ks], kf, s, 0, 0, 0);
      }
      sf[mt] = s;
    }
    __builtin_amdgcn_s_setprio(0);

    // ---- consume bias(t) ----
    float sv[4][4];
#pragma unroll
    for (int mt = 0; mt < 4; ++mt) {
      const bool on = mkv[mt] != 0;
#pragma unroll
      for (int r = 0; r < 4; ++r) {
        const float x = fmaf(sf[mt][r], FACTOR, rbv[mt][r] + dbv[mt][r]);
        sv[mt][r] = on ? x : -INFINITY;
      }
    }

    // ---- issue bias(t+1), pinned live until next tile's consume ----
    if (m0 < 960) {
#pragma unroll
      for (int mt = 0; mt < 4; ++mt) {
        const int m = m0 + 64 + mt * 16 + l16;
        mkv[mt] = msk[mbase + m];
#pragma unroll
        for (int r = 0; r < 4; ++r) {
          rbv[mt][r] = rbf[rb_base[r] + m];
          dbv[mt][r] = Dm[db_base[r] + m];
        }
      }
    }
    KEEP_LOADS();

    // ---- online softmax ----
    float psv[4][4];
#pragma unroll
    for (int r = 0; r < 4; ++r) {
      float tm = fmaxf(fmaxf(sv[0][r], sv[1][r]), fmaxf(sv[2][r], sv[3][r]));
      tm = fmaxf(tm, __shfl_xor(tm, 1));
      tm = fmaxf(tm, __shfl_xor(tm, 2));
      tm = fmaxf(tm, __shfl_xor(tm, 4));
      tm = fmaxf(tm, __shfl_xor(tm, 8));
      const float mn = fmaxf(m_run[r], tm);
      const float sc = (mn == m_run[r]) ? 1.f : __expf(m_run[r] - mn);
      m_run[r] = mn;
      float rs = 0.f;
#pragma unroll
      for (int mt = 0; mt < 4; ++mt) {
        const float s = sv[mt][r];
        const float p = (s == -INFINITY) ? 0.f : __expf(s - mn);
        psv[mt][r] = p;
        rs += p;
      }
      rs += __shfl_xor(rs, 1);
      rs += __shfl_xor(rs, 2);
      rs += __shfl_xor(rs, 4);
      rs += __shfl_xor(rs, 8);
      l_run[r] = l_run[r] * sc + rs;
#pragma unroll
      for (int vt = 0; vt < 8; ++vt) acc[vt][r] *= sc;
    }

    // ---- P -> LDS (per-wave region), then PV ----
#pragma unroll
    for (int mt = 0; mt < 4; ++mt)
#pragma unroll
      for (int r = 0; r < 4; ++r)
        PsL[(w * 16 + lg * 4 + r) * PP + mt * 16 + l16] = f2bf(psv[mt][r]);
    asm volatile("s_waitcnt lgkmcnt(0)" ::: "memory");
    __builtin_amdgcn_sched_barrier(0);

    s16x8 pf[2];
#pragma unroll
    for (int ks = 0; ks < 2; ++ks)
      pf[ks] = *(const s16x8*)&PsL[(w * 16 + l16) * PP + ks * 32 + lg * 8];
    __builtin_amdgcn_s_setprio(1);
#pragma unroll
    for (int vt = 0; vt < 8; ++vt) {
#pragma unroll
      for (int ks = 0; ks < 2; ++ks) {
        const s16x8 vf = *(const s16x8*)&VtL[(vt * 16 + l16) * VP + ks * 32 + lg * 8];
        acc[vt] = __builtin_amdgcn_mfma_f32_16x16x32_bf16(pf[ks], vf, acc[vt], 0, 0, 0);
      }
    }
    __builtin_amdgcn_s_setprio(0);
  }

  float inv[4];
#pragma unroll
  for (int r = 0; r < 4; ++r) inv[r] = (l_run[r] > 0.f) ? 1.f / l_run[r] : 0.f;

#pragma unroll
  for (int vt = 0; vt < 8; ++vt) {
    const int vdim = vt * 16 + l16;
#pragma unroll
    for (int r = 0; r < 4; ++r) {
      const int q = q0 + lg * 4 + r;
      const float o = acc[vt][r] * inv[r];
      if (vdim < 32) {
        Hres[((size_t)(b * 1024 + q)) * 512 + h * 32 + vdim] = o;
      } else {
        const int ix = vdim - 32, cd = ix >> 5, kq = ix & 31;
        Vres[(((size_t)(b * 1024 + q)) * 3 + cd) * 512 + h * 32 + kq] = o;
      }
    }
  }
}

// ---------------------------------------------------------------------------
extern "C" void kernel_launch(void* const* d_in, const int* in_sizes, int n_in,
                              void* d_out, int out_size, void* d_ws, size_t ws_size,
                              hipStream_t stream)
{
  const float* Hp  = (const float*)d_in[0];
  const float* Vp  = (const float*)d_in[1];
  const float* Db  = (const float*)d_in[2];
  const float* rbf = (const float*)d_in[3];
  const int*   Hm  = (const int*)d_in[4];
  const float* Wq  = (const float*)d_in[5];
  const float* bq  = (const float*)d_in[6];
  const float* Wk  = (const float*)d_in[7];
  const float* bk  = (const float*)d_in[8];
  const float* Wv  = (const float*)d_in[9];
  const float* bv  = (const float*)d_in[10];
  const float* Wvv = (const float*)d_in[11];
  const float* Wo  = (const float*)d_in[12];
  const float* bo  = (const float*)d_in[13];
  const float* Wvo = (const float*)d_in[14];
  float* out = (float*)d_out;

  // ws (bytes): Qb 16M | Kb 16M | Vt 16M | Hres 8M | Vres 24M = 80MB
  if (ws_size < (size_t)83886080) return;
  unsigned short* Qb = (unsigned short*)d_ws;
  unsigned short* Kb = Qb + 8388608;
  unsigned short* Vt = Kb + 8388608;
  float* Hres = (float*)(Vt + 8388608);
  float* Vres = Hres + 2097152;

  const dim3 blk(256);

  gemm_mfma<<<dim3(32, 16), blk, 0, stream>>>(Hp, Wq, bq, Qb, 4096, 2048, 512, 3);
  gemm_mfma<<<dim3(32, 16), blk, 0, stream>>>(Hp, Wk, bk, Kb, 4096, 2048, 512, 3);
  gemm_mfma<<<dim3(4, 32),  blk, 0, stream>>>(Wv, Hp, bv, Vt, 512, 4096, 512, 4);
  gemm_mfma<<<dim3(4, 96),  blk, 0, stream>>>(Wvv, Vp, nullptr, Vt, 512, 12288, 512, 5);

  attn_mfma<<<dim3(16, 64), blk, 0, stream>>>(Qb, Kb, Vt, rbf, Db, Hm, Hres, Vres);

  gemm_mfma<<<dim3(32, 4), blk, 0, stream>>>(Hres, Wo, bo, out, 4096, 512, 512, 0);
  gemm_mfma<<<dim3(96, 4), blk, 0, stream>>>(Vres, Wvo, nullptr, out + 2097152, 12288, 512, 512, 0);
}

// Round 10
// 316.668 us; speedup vs baseline: 1.3375x; 1.2876x over previous
//
#include <hip/hip_runtime.h>
#include <cmath>

#define FACTOR 0.08838834764831845f

typedef short s16x8 __attribute__((ext_vector_type(8)));
typedef float f32x4 __attribute__((ext_vector_type(4)));
typedef unsigned int u32;

#define KEEP_LOADS() do { asm volatile("" ::: "memory"); __builtin_amdgcn_sched_barrier(0); } while (0)

__device__ __forceinline__ unsigned short f2bf(float x) {
  unsigned int u = __float_as_uint(x);
  u += 0x7FFFu + ((u >> 16) & 1u);
  return (unsigned short)(u >> 16);
}

__device__ __forceinline__ s16x8 pack8(float4 a, float4 b) {
  s16x8 r;
  r[0] = (short)f2bf(a.x); r[1] = (short)f2bf(a.y);
  r[2] = (short)f2bf(a.z); r[3] = (short)f2bf(a.w);
  r[4] = (short)f2bf(b.x); r[5] = (short)f2bf(b.y);
  r[6] = (short)f2bf(b.z); r[7] = (short)f2bf(b.w);
  return r;
}

// async global->LDS DMA, 16B per lane; dest = lds_base + lane*16 (HW rule).
__device__ __forceinline__ void gload_lds16(const void* g, void* l) {
  __builtin_amdgcn_global_load_lds(
      (const __attribute__((address_space(1))) u32*)g,
      (__attribute__((address_space(3))) u32*)l, 16, 0, 0);
}

// ---------------------------------------------------------------------------
// MFMA GEMM (unchanged from R9-passing version).
// mode 0: f32 C | mode 3: bf16 C | mode 4/5: Vt scatters (5 = fused V transpose)
// ---------------------------------------------------------------------------
__global__ __launch_bounds__(256) void gemm_mfma(
    const float* __restrict__ A, const float* __restrict__ B,
    const float* __restrict__ bias, void* __restrict__ C,
    int M, int N, int K, int mode)
{
  __shared__ unsigned short As[128 * 72];
  __shared__ unsigned short Bs[128 * 72];

  const int tid = threadIdx.x;
  const int w = tid >> 6, lane = tid & 63;
  const int l16 = lane & 15, lg = lane >> 4;
  const int wm = w >> 1, wn = w & 1;
  const int m0 = blockIdx.x * 128;
  const int n0 = blockIdx.y * 128;

  const int sr = tid >> 3;
  const int sc = (tid & 7) * 8;

  float4 ar[4][2], br[4][2];

  auto issue = [&](int k0) {
#pragma unroll
    for (int i = 0; i < 4; ++i) {
      const int rr = i * 32 + sr;
      const float* ap = A + (size_t)(m0 + rr) * K + k0 + sc;
      ar[i][0] = *(const float4*)ap;
      ar[i][1] = *(const float4*)(ap + 4);
      const float* bp;
      if (mode == 5) {
        const int t = n0 + rr;
        const int q3 = t >> 10, n = t & 1023;
        const int bb = q3 / 3, cd = q3 - 3 * bb;
        bp = B + (((size_t)(bb * 1024 + n)) * 3 + cd) * 512 + k0 + sc;
      } else {
        bp = B + (size_t)(n0 + rr) * K + k0 + sc;
      }
      br[i][0] = *(const float4*)bp;
      br[i][1] = *(const float4*)(bp + 4);
    }
  };

  f32x4 acc[4][4];
#pragma unroll
  for (int mt = 0; mt < 4; ++mt)
#pragma unroll
    for (int nt = 0; nt < 4; ++nt)
#pragma unroll
      for (int r = 0; r < 4; ++r) acc[mt][nt][r] = 0.f;

  issue(0);

#pragma unroll 1
  for (int k0 = 0; k0 < K; k0 += 64) {
    __builtin_amdgcn_s_barrier();
#pragma unroll
    for (int i = 0; i < 4; ++i) {
      const int rr = i * 32 + sr;
      *(s16x8*)&As[rr * 72 + sc] = pack8(ar[i][0], ar[i][1]);
      *(s16x8*)&Bs[rr * 72 + sc] = pack8(br[i][0], br[i][1]);
    }
    asm volatile("s_waitcnt lgkmcnt(0)" ::: "memory");
    __builtin_amdgcn_s_barrier();
    if (k0 + 64 < K) issue(k0 + 64);
    KEEP_LOADS();

#pragma unroll
    for (int ks = 0; ks < 2; ++ks) {
      s16x8 af[4], bf[4];
#pragma unroll
      for (int mt = 0; mt < 4; ++mt)
        af[mt] = *(const s16x8*)&As[(wm * 64 + mt * 16 + l16) * 72 + ks * 32 + lg * 8];
#pragma unroll
      for (int nt = 0; nt < 4; ++nt)
        bf[nt] = *(const s16x8*)&Bs[(wn * 64 + nt * 16 + l16) * 72 + ks * 32 + lg * 8];
#pragma unroll
      for (int mt = 0; mt < 4; ++mt)
#pragma unroll
        for (int nt = 0; nt < 4; ++nt)
          acc[mt][nt] = __builtin_amdgcn_mfma_f32_16x16x32_bf16(af[mt], bf[nt], acc[mt][nt], 0, 0, 0);
    }
  }

  const int rbase = m0 + wm * 64;
  const int cbase = n0 + wn * 64;

  if (mode == 0 || mode == 3) {
#pragma unroll
    for (int nt = 0; nt < 4; ++nt) {
      const int c = cbase + nt * 16 + l16;
      const float bb = bias ? bias[c] : 0.f;
#pragma unroll
      for (int mt = 0; mt < 4; ++mt) {
#pragma unroll
        for (int r = 0; r < 4; ++r) {
          const int row = rbase + mt * 16 + lg * 4 + r;
          const float v = acc[mt][nt][r] + bb;
          if (mode == 0) ((float*)C)[(size_t)row * N + c] = v;
          else           ((unsigned short*)C)[(size_t)row * N + c] = f2bf(v);
        }
      }
    }
  } else {
    unsigned short* Cb = (unsigned short*)C;
#pragma unroll
    for (int mt = 0; mt < 4; ++mt) {
#pragma unroll
      for (int r = 0; r < 4; ++r) {
        const int ch = rbase + mt * 16 + lg * 4 + r;
        const float bb = bias ? bias[ch] : 0.f;
        const int h = ch >> 5, dq = ch & 31;
#pragma unroll
        for (int nt = 0; nt < 4; ++nt) {
          const int t = cbase + nt * 16 + l16;
          size_t off;
          if (mode == 4) {
            const int b = t >> 10, n = t & 1023;
            off = (((size_t)(b * 16 + h)) * 128 + dq) * 1024 + n;
          } else {
            const int q3 = t >> 10, n = t & 1023;
            const int b = q3 / 3, cd = q3 - 3 * b;
            off = (((size_t)(b * 16 + h)) * 128 + 32 + cd * 32 + dq) * 1024 + n;
          }
          Cb[off] = f2bf(acc[mt][nt][r] + bb);
        }
      }
    }
  }
}

// ---------------------------------------------------------------------------
// MFMA flash attention, DMA-staged (global_load_lds), m-tile 32, double-buffered.
// All staging (K, V, rbf, Dm, mask) via async DMA -> no VGPR staging, no spills,
// full MLP. K/V swizzled (XOR chunk) for conflict-free b128 reads.
// One vmcnt(0)+barrier per tile.
// ---------------------------------------------------------------------------
__global__ __launch_bounds__(256, 2) void attn_mfma(
    const unsigned short* __restrict__ Qg, const unsigned short* __restrict__ Kg,
    const unsigned short* __restrict__ Vtg, const float* __restrict__ rbf,
    const float* __restrict__ Dm, const int* __restrict__ msk,
    float* __restrict__ Hres, float* __restrict__ Vres)
{
  __shared__ unsigned short KsL[2][32 * 128];   // [m 32][256B row], chunk^=(row&7)
  __shared__ unsigned short VtL[2][128 * 32];   // [d 128][64B row], chunk^=((row>>1)&3)
  __shared__ float          RbL[2][64 * 32];    // [q 64][m 32] linear
  __shared__ float          DmL[2][64 * 32];
  __shared__ int            MsL[1024];          // whole-b mask, staged once
  __shared__ unsigned short PsL[64 * 40];       // P, pitch 40

  const int tid  = threadIdx.x;
  const int w    = tid >> 6;
  const int lane = tid & 63;
  const int l16  = lane & 15;
  const int lg   = lane >> 4;

  const int bh = blockIdx.y;
  const int b  = bh >> 4;
  const int h  = bh & 15;
  const int r0 = blockIdx.x * 64;
  const int q0 = r0 + w * 16;

  // ---- Q fragments (registers, whole pass) ----
  s16x8 qf[4];
  {
    const unsigned short* qp = Qg + ((size_t)(b * 1024 + q0 + l16)) * 2048 + h * 128 + lg * 8;
#pragma unroll
    for (int ks = 0; ks < 4; ++ks) qf[ks] = *(const s16x8*)(qp + ks * 32);
  }

  float m_run[4], l_run[4];
  f32x4 acc[8];
#pragma unroll
  for (int r = 0; r < 4; ++r) { m_run[r] = -INFINITY; l_run[r] = 0.f; }
#pragma unroll
  for (int vt = 0; vt < 8; ++vt)
#pragma unroll
    for (int r = 0; r < 4; ++r) acc[vt][r] = 0.f;

  // ---- DMA: one tile = 8 instr/wave (K2 + V2 + rbf2 + Dm2) ----
  auto issue_tile = [&](int t, int bf) {
    const int m0 = t * 32;
#pragma unroll
    for (int jj = 0; jj < 2; ++jj) {
      const int j = w * 2 + jj;            // instr index 0..7
      {
        const int row = j * 4 + (lane >> 4);               // K row 0..31
        const int ch  = (lane & 15) ^ (row & 7);           // swizzled src chunk
        gload_lds16(Kg + ((size_t)(b * 1024 + m0 + row)) * 2048 + h * 128 + ch * 8,
                    &KsL[bf][j * 512]);
      }
      {
        const int row = j * 16 + (lane >> 2);              // V row 0..127
        const int ch  = (lane & 3) ^ ((row >> 1) & 3);
        gload_lds16(Vtg + ((size_t)(bh * 128 + row)) * 1024 + m0 + ch * 8,
                    &VtL[bf][j * 512]);
      }
      {
        const int row = j * 8 + (lane >> 3);               // bias row 0..63
        const int ch  = lane & 7;
        gload_lds16(rbf + ((size_t)(bh * 1024 + r0 + row)) * 1024 + m0 + ch * 4,
                    &RbL[bf][j * 256]);
      }
      {
        const int row = j * 8 + (lane >> 3);
        const int ch  = lane & 7;
        gload_lds16(Dm + ((size_t)(b * 1024 + r0 + row)) * 1024 + m0 + ch * 4,
                    &DmL[bf][j * 256]);
      }
    }
  };

  // ---- prologue: mask (whole b) + tile 0 ----
  gload_lds16(msk + b * 1024 + w * 256 + lane * 4, &MsL[w * 256]);
  issue_tile(0, 0);

#pragma unroll 1
  for (int t = 0; t < 32; ++t) {
    const int bf = t & 1;
    asm volatile("s_waitcnt vmcnt(0)" ::: "memory");   // own DMAs landed
    __builtin_amdgcn_s_barrier();                      // all waves' DMAs landed
    if (t < 31) issue_tile(t + 1, bf ^ 1);             // in flight through this tile
    __builtin_amdgcn_sched_barrier(0);

    const int m0 = t * 32;

    // ---- QK scores (2 m-subtiles x 4 k-steps) ----
    __builtin_amdgcn_s_setprio(1);
    f32x4 sf[2];
#pragma unroll
    for (int mt = 0; mt < 2; ++mt) {
      f32x4 s;
#pragma unroll
      for (int r = 0; r < 4; ++r) s[r] = 0.f;
      const int row = mt * 16 + l16;
#pragma unroll
      for (int ks = 0; ks < 4; ++ks) {
        const s16x8 kf = *(const s16x8*)&KsL[bf][row * 128 + (((ks * 4 + lg) ^ (row & 7)) * 8)];
        s = __builtin_amdgcn_mfma_f32_16x16x32_bf16(qf[ks], kf, s, 0, 0, 0);
      }
      sf[mt] = s;
    }
    __builtin_amdgcn_s_setprio(0);

    // ---- bias + mask (from LDS) ----
    float sv[2][4];
#pragma unroll
    for (int mt = 0; mt < 2; ++mt) {
      const bool on = MsL[m0 + mt * 16 + l16] != 0;
#pragma unroll
      for (int r = 0; r < 4; ++r) {
        const int ql = w * 16 + lg * 4 + r;
        const float bb = RbL[bf][ql * 32 + mt * 16 + l16] + DmL[bf][ql * 32 + mt * 16 + l16];
        const float x = fmaf(sf[mt][r], FACTOR, bb);
        sv[mt][r] = on ? x : -INFINITY;
      }
    }

    // ---- online softmax ----
    float psv[2][4];
#pragma unroll
    for (int r = 0; r < 4; ++r) {
      float tm = fmaxf(sv[0][r], sv[1][r]);
      tm = fmaxf(tm, __shfl_xor(tm, 1));
      tm = fmaxf(tm, __shfl_xor(tm, 2));
      tm = fmaxf(tm, __shfl_xor(tm, 4));
      tm = fmaxf(tm, __shfl_xor(tm, 8));
      const float mn = fmaxf(m_run[r], tm);
      const float sc = (mn == m_run[r]) ? 1.f : __expf(m_run[r] - mn);
      m_run[r] = mn;
      float rs = 0.f;
#pragma unroll
      for (int mt = 0; mt < 2; ++mt) {
        const float s = sv[mt][r];
        const float p = (s == -INFINITY) ? 0.f : __expf(s - mn);
        psv[mt][r] = p;
        rs += p;
      }
      rs += __shfl_xor(rs, 1);
      rs += __shfl_xor(rs, 2);
      rs += __shfl_xor(rs, 4);
      rs += __shfl_xor(rs, 8);
      l_run[r] = l_run[r] * sc + rs;
#pragma unroll
      for (int vt = 0; vt < 8; ++vt) acc[vt][r] *= sc;
    }

    // ---- P -> LDS (per-wave region), PV (1 k-step) ----
#pragma unroll
    for (int mt = 0; mt < 2; ++mt)
#pragma unroll
      for (int r = 0; r < 4; ++r)
        PsL[(w * 16 + lg * 4 + r) * 40 + mt * 16 + l16] = f2bf(psv[mt][r]);
    asm volatile("s_waitcnt lgkmcnt(0)" ::: "memory");
    __builtin_amdgcn_sched_barrier(0);

    const s16x8 pf = *(const s16x8*)&PsL[(w * 16 + l16) * 40 + lg * 8];
    __builtin_amdgcn_s_setprio(1);
#pragma unroll
    for (int vt = 0; vt < 8; ++vt) {
      const int row = vt * 16 + l16;
      const s16x8 vf = *(const s16x8*)&VtL[bf][row * 32 + ((lg ^ ((row >> 1) & 3)) * 8)];
      acc[vt] = __builtin_amdgcn_mfma_f32_16x16x32_bf16(pf, vf, acc[vt], 0, 0, 0);
    }
    __builtin_amdgcn_s_setprio(0);
  }

  // ---- epilogue ----
  float inv[4];
#pragma unroll
  for (int r = 0; r < 4; ++r) inv[r] = (l_run[r] > 0.f) ? 1.f / l_run[r] : 0.f;

#pragma unroll
  for (int vt = 0; vt < 8; ++vt) {
    const int vdim = vt * 16 + l16;
#pragma unroll
    for (int r = 0; r < 4; ++r) {
      const int q = q0 + lg * 4 + r;
      const float o = acc[vt][r] * inv[r];
      if (vdim < 32) {
        Hres[((size_t)(b * 1024 + q)) * 512 + h * 32 + vdim] = o;
      } else {
        const int ix = vdim - 32, cd = ix >> 5, kq = ix & 31;
        Vres[(((size_t)(b * 1024 + q)) * 3 + cd) * 512 + h * 32 + kq] = o;
      }
    }
  }
}

// ---------------------------------------------------------------------------
extern "C" void kernel_launch(void* const* d_in, const int* in_sizes, int n_in,
                              void* d_out, int out_size, void* d_ws, size_t ws_size,
                              hipStream_t stream)
{
  const float* Hp  = (const float*)d_in[0];
  const float* Vp  = (const float*)d_in[1];
  const float* Db  = (const float*)d_in[2];
  const float* rbf = (const float*)d_in[3];
  const int*   Hm  = (const int*)d_in[4];
  const float* Wq  = (const float*)d_in[5];
  const float* bq  = (const float*)d_in[6];
  const float* Wk  = (const float*)d_in[7];
  const float* bk  = (const float*)d_in[8];
  const float* Wv  = (const float*)d_in[9];
  const float* bv  = (const float*)d_in[10];
  const float* Wvv = (const float*)d_in[11];
  const float* Wo  = (const float*)d_in[12];
  const float* bo  = (const float*)d_in[13];
  const float* Wvo = (const float*)d_in[14];
  float* out = (float*)d_out;

  // ws (bytes): Qb 16M | Kb 16M | Vt 16M | Hres 8M | Vres 24M = 80MB
  if (ws_size < (size_t)83886080) return;
  unsigned short* Qb = (unsigned short*)d_ws;
  unsigned short* Kb = Qb + 8388608;
  unsigned short* Vt = Kb + 8388608;
  float* Hres = (float*)(Vt + 8388608);
  float* Vres = Hres + 2097152;

  const dim3 blk(256);

  gemm_mfma<<<dim3(32, 16), blk, 0, stream>>>(Hp, Wq, bq, Qb, 4096, 2048, 512, 3);
  gemm_mfma<<<dim3(32, 16), blk, 0, stream>>>(Hp, Wk, bk, Kb, 4096, 2048, 512, 3);
  gemm_mfma<<<dim3(4, 32),  blk, 0, stream>>>(Wv, Hp, bv, Vt, 512, 4096, 512, 4);
  gemm_mfma<<<dim3(4, 96),  blk, 0, stream>>>(Wvv, Vp, nullptr, Vt, 512, 12288, 512, 5);

  attn_mfma<<<dim3(16, 64), blk, 0, stream>>>(Qb, Kb, Vt, rbf, Db, Hm, Hres, Vres);

  gemm_mfma<<<dim3(32, 4), blk, 0, stream>>>(Hres, Wo, bo, out, 4096, 512, 512, 0);
  gemm_mfma<<<dim3(96, 4), blk, 0, stream>>>(Vres, Wvo, nullptr, out + 2097152, 12288, 512, 512, 0);
}

// Round 12
// 298.391 us; speedup vs baseline: 1.4194x; 1.0613x over previous
//
#include <hip/hip_runtime.h>
#include <cmath>

#define FACTOR 0.08838834764831845f

typedef short s16x8 __attribute__((ext_vector_type(8)));
typedef float f32x4 __attribute__((ext_vector_type(4)));
typedef float f32x16 __attribute__((ext_vector_type(16)));
typedef unsigned int u32;

#define KEEP_LOADS() do { asm volatile("" ::: "memory"); __builtin_amdgcn_sched_barrier(0); } while (0)

__device__ __forceinline__ unsigned short f2bf(float x) {
  unsigned int u = __float_as_uint(x);
  u += 0x7FFFu + ((u >> 16) & 1u);
  return (unsigned short)(u >> 16);
}

__device__ __forceinline__ s16x8 pack8(float4 a, float4 b) {
  s16x8 r;
  r[0] = (short)f2bf(a.x); r[1] = (short)f2bf(a.y);
  r[2] = (short)f2bf(a.z); r[3] = (short)f2bf(a.w);
  r[4] = (short)f2bf(b.x); r[5] = (short)f2bf(b.y);
  r[6] = (short)f2bf(b.z); r[7] = (short)f2bf(b.w);
  return r;
}

__device__ __forceinline__ void gload_lds16(const void* g, void* l) {
  __builtin_amdgcn_global_load_lds(
      (const __attribute__((address_space(1))) u32*)g,
      (__attribute__((address_space(3))) u32*)l, 16, 0, 0);
}

// ---- 32-lane reductions: 4 DPP (VALU) + 1 ds_swizzle(xor16) ----
template <int CTRL>
__device__ __forceinline__ float dppmax(float x) {
  int y = __builtin_amdgcn_mov_dpp(__float_as_int(x), CTRL, 0xf, 0xf, false);
  return fmaxf(x, __int_as_float(y));
}
template <int CTRL>
__device__ __forceinline__ float dppadd(float x) {
  int y = __builtin_amdgcn_mov_dpp(__float_as_int(x), CTRL, 0xf, 0xf, false);
  return x + __int_as_float(y);
}
__device__ __forceinline__ float swz16(float x) {
  return __int_as_float(__builtin_amdgcn_ds_swizzle(__float_as_int(x), 0x401F));
}
__device__ __forceinline__ float red32max(float x) {
  x = dppmax<0xB1>(x);    // quad_perm xor1
  x = dppmax<0x4E>(x);    // quad_perm xor2
  x = dppmax<0x141>(x);   // row_half_mirror
  x = dppmax<0x140>(x);   // row_mirror
  return fmaxf(x, swz16(x));  // xor16
}
__device__ __forceinline__ float red32add(float x) {
  x = dppadd<0xB1>(x);
  x = dppadd<0x4E>(x);
  x = dppadd<0x141>(x);
  x = dppadd<0x140>(x);
  return x + swz16(x);
}

// ---------------------------------------------------------------------------
// MFMA GEMM (unchanged, R10-passing).
// mode 0: f32 C | mode 3: bf16 C | mode 4/5: Vt scatters (5 = fused V transpose)
// ---------------------------------------------------------------------------
__global__ __launch_bounds__(256) void gemm_mfma(
    const float* __restrict__ A, const float* __restrict__ B,
    const float* __restrict__ bias, void* __restrict__ C,
    int M, int N, int K, int mode)
{
  __shared__ unsigned short As[128 * 72];
  __shared__ unsigned short Bs[128 * 72];

  const int tid = threadIdx.x;
  const int w = tid >> 6, lane = tid & 63;
  const int l16 = lane & 15, lg = lane >> 4;
  const int wm = w >> 1, wn = w & 1;
  const int m0 = blockIdx.x * 128;
  const int n0 = blockIdx.y * 128;

  const int sr = tid >> 3;
  const int sc = (tid & 7) * 8;

  float4 ar[4][2], br[4][2];

  auto issue = [&](int k0) {
#pragma unroll
    for (int i = 0; i < 4; ++i) {
      const int rr = i * 32 + sr;
      const float* ap = A + (size_t)(m0 + rr) * K + k0 + sc;
      ar[i][0] = *(const float4*)ap;
      ar[i][1] = *(const float4*)(ap + 4);
      const float* bp;
      if (mode == 5) {
        const int t = n0 + rr;
        const int q3 = t >> 10, n = t & 1023;
        const int bb = q3 / 3, cd = q3 - 3 * bb;
        bp = B + (((size_t)(bb * 1024 + n)) * 3 + cd) * 512 + k0 + sc;
      } else {
        bp = B + (size_t)(n0 + rr) * K + k0 + sc;
      }
      br[i][0] = *(const float4*)bp;
      br[i][1] = *(const float4*)(bp + 4);
    }
  };

  f32x4 acc[4][4];
#pragma unroll
  for (int mt = 0; mt < 4; ++mt)
#pragma unroll
    for (int nt = 0; nt < 4; ++nt)
#pragma unroll
      for (int r = 0; r < 4; ++r) acc[mt][nt][r] = 0.f;

  issue(0);

#pragma unroll 1
  for (int k0 = 0; k0 < K; k0 += 64) {
    __builtin_amdgcn_s_barrier();
#pragma unroll
    for (int i = 0; i < 4; ++i) {
      const int rr = i * 32 + sr;
      *(s16x8*)&As[rr * 72 + sc] = pack8(ar[i][0], ar[i][1]);
      *(s16x8*)&Bs[rr * 72 + sc] = pack8(br[i][0], br[i][1]);
    }
    asm volatile("s_waitcnt lgkmcnt(0)" ::: "memory");
    __builtin_amdgcn_s_barrier();
    if (k0 + 64 < K) issue(k0 + 64);
    KEEP_LOADS();

#pragma unroll
    for (int ks = 0; ks < 2; ++ks) {
      s16x8 af[4], bf[4];
#pragma unroll
      for (int mt = 0; mt < 4; ++mt)
        af[mt] = *(const s16x8*)&As[(wm * 64 + mt * 16 + l16) * 72 + ks * 32 + lg * 8];
#pragma unroll
      for (int nt = 0; nt < 4; ++nt)
        bf[nt] = *(const s16x8*)&Bs[(wn * 64 + nt * 16 + l16) * 72 + ks * 32 + lg * 8];
#pragma unroll
      for (int mt = 0; mt < 4; ++mt)
#pragma unroll
        for (int nt = 0; nt < 4; ++nt)
          acc[mt][nt] = __builtin_amdgcn_mfma_f32_16x16x32_bf16(af[mt], bf[nt], acc[mt][nt], 0, 0, 0);
    }
  }

  const int rbase = m0 + wm * 64;
  const int cbase = n0 + wn * 64;

  if (mode == 0 || mode == 3) {
#pragma unroll
    for (int nt = 0; nt < 4; ++nt) {
      const int c = cbase + nt * 16 + l16;
      const float bb = bias ? bias[c] : 0.f;
#pragma unroll
      for (int mt = 0; mt < 4; ++mt) {
#pragma unroll
        for (int r = 0; r < 4; ++r) {
          const int row = rbase + mt * 16 + lg * 4 + r;
          const float v = acc[mt][nt][r] + bb;
          if (mode == 0) ((float*)C)[(size_t)row * N + c] = v;
          else           ((unsigned short*)C)[(size_t)row * N + c] = f2bf(v);
        }
      }
    }
  } else {
    unsigned short* Cb = (unsigned short*)C;
#pragma unroll
    for (int mt = 0; mt < 4; ++mt) {
#pragma unroll
      for (int r = 0; r < 4; ++r) {
        const int ch = rbase + mt * 16 + lg * 4 + r;
        const float bb = bias ? bias[ch] : 0.f;
        const int h = ch >> 5, dq = ch & 31;
#pragma unroll
        for (int nt = 0; nt < 4; ++nt) {
          const int t = cbase + nt * 16 + l16;
          size_t off;
          if (mode == 4) {
            const int b = t >> 10, n = t & 1023;
            off = (((size_t)(b * 16 + h)) * 128 + dq) * 1024 + n;
          } else {
            const int q3 = t >> 10, n = t & 1023;
            const int b = q3 / 3, cd = q3 - 3 * b;
            off = (((size_t)(b * 16 + h)) * 128 + 32 + cd * 32 + dq) * 1024 + n;
          }
          Cb[off] = f2bf(acc[mt][nt][r] + bb);
        }
      }
    }
  }
}

// ---------------------------------------------------------------------------
// Flash attention, 32x32x16 MFMA, 32 q/wave, q-tile 128/block, m-tile 32.
// K/V: DMA -> LDS in slab-transposed placement (conflict-free b128 reads).
// Bias: direct global->reg (no LDS). Softmax: DPP reductions. Defer-max THR=8.
// 32x32 layouts: A row=lane&31, k=(lane>>5)*8+e; B col=lane&31, same k;
// C/D col=lane&31, row=(reg&3)+8*(reg>>2)+4*(lane>>5).
// ---------------------------------------------------------------------------
__global__ __launch_bounds__(256, 2) void attn_mfma(
    const unsigned short* __restrict__ Qg, const unsigned short* __restrict__ Kg,
    const unsigned short* __restrict__ Vtg, const float* __restrict__ rbf,
    const float* __restrict__ Dm, const int* __restrict__ msk,
    float* __restrict__ Hres, float* __restrict__ Vres)
{
  __shared__ unsigned short KsL[2][4096];   // slabs: ko(16) x m(32) x 16B
  __shared__ unsigned short VtL[2][4096];   // dt(4) x o(4) x d'(32) x 16B
  __shared__ unsigned short PsL[4][32 * 40];
  __shared__ int MsL[1024];

  const int tid  = threadIdx.x;
  const int w    = tid >> 6;
  const int lane = tid & 63;
  const int l32  = lane & 31;
  const int hi   = lane >> 5;

  const int bh = blockIdx.y;
  const int b  = bh >> 4;
  const int h  = bh & 15;
  const int q0 = blockIdx.x * 128 + w * 32;

  // ---- Q fragments: 8 k-steps x 8 bf16 ----
  s16x8 qf[8];
  {
    const unsigned short* qp = Qg + ((size_t)(b * 1024 + q0 + l32)) * 2048 + h * 128 + hi * 8;
#pragma unroll
    for (int ks = 0; ks < 8; ++ks) qf[ks] = *(const s16x8*)(qp + ks * 16);
  }

  f32x16 acc[4];
  float m_run[16], l_run[16];
#pragma unroll
  for (int dt = 0; dt < 4; ++dt)
#pragma unroll
    for (int r = 0; r < 16; ++r) acc[dt][r] = 0.f;
#pragma unroll
  for (int r = 0; r < 16; ++r) { m_run[r] = -INFINITY; l_run[r] = 0.f; }

  const float* rbB = rbf + ((size_t)bh * 1024 + q0 + 4 * hi) * 1024 + l32;
  const float* dbB = Dm  + ((size_t)b  * 1024 + q0 + 4 * hi) * 1024 + l32;

  // ---- DMA one tile: 4 instr/wave (2 K + 2 V), slab-transposed placement ----
  auto issue_kv = [&](int t, int bf) {
    const int m0 = t * 32;
#pragma unroll
    for (int jj = 0; jj < 2; ++jj) {
      const int i = w * 2 + jj;            // 0..7
      // K slab: unit (m=l32, ko=2i+hi) <- Kg[b][m0+l32][k=(2i+hi)*8 ..+8]
      gload_lds16(Kg + ((size_t)(b * 1024 + m0 + l32)) * 2048 + h * 128 + (2 * i + hi) * 8,
                  &KsL[bf][i * 512]);
      // V slab: unit (dt=i>>1, o=(i&1)*2+hi, d'=l32) <- Vt[bh][dt*32+l32][m0+o*8 ..+8]
      gload_lds16(Vtg + ((size_t)(bh * 128 + (i >> 1) * 32 + l32)) * 1024 + m0 + ((i & 1) * 2 + hi) * 8,
                  &VtL[bf][i * 512]);
    }
  };

  // ---- prologue: mask (whole b) + tile 0 ----
  gload_lds16(msk + b * 1024 + w * 256 + lane * 4, &MsL[w * 256]);
  issue_kv(0, 0);

#pragma unroll 1
  for (int t = 0; t < 32; ++t) {
    const int bf = t & 1;
    const int m0 = t * 32;

    asm volatile("s_waitcnt vmcnt(0)" ::: "memory");   // this wave's DMAs landed
    __builtin_amdgcn_s_barrier();                      // all waves' DMAs landed

    // ---- issue bias loads (consumed after QK), then next tile's DMA ----
    float rb[16], db[16];
#pragma unroll
    for (int r = 0; r < 16; ++r) {
      const int roff = (r & 3) + 8 * (r >> 2);
      rb[r] = rbB[(size_t)roff * 1024 + m0];
      db[r] = dbB[(size_t)roff * 1024 + m0];
    }
    if (t < 31) issue_kv(t + 1, bf ^ 1);
    __builtin_amdgcn_sched_barrier(0);

    // ---- QK: 8 MFMA 32x32x16 ----
    f32x16 sf;
#pragma unroll
    for (int r = 0; r < 16; ++r) sf[r] = 0.f;
    __builtin_amdgcn_s_setprio(1);
#pragma unroll
    for (int ks = 0; ks < 8; ++ks) {
      const s16x8 kf = *(const s16x8*)&KsL[bf][(ks * 2 + hi) * 256 + l32 * 8];
      sf = __builtin_amdgcn_mfma_f32_32x32x16_bf16(qf[ks], kf, sf, 0, 0, 0);
    }
    __builtin_amdgcn_s_setprio(0);

    // ---- bias + mask (mask depends only on lane's m) ----
    const bool on = MsL[m0 + l32] != 0;
    float sv[16];
#pragma unroll
    for (int r = 0; r < 16; ++r)
      sv[r] = on ? fmaf(sf[r], FACTOR, rb[r] + db[r]) : -INFINITY;

    // ---- online softmax (16 rows/lane, DPP reductions over 32 lanes) ----
    float tmax[16];
    bool ok = true;
#pragma unroll
    for (int r = 0; r < 16; ++r) {
      tmax[r] = red32max(sv[r]);
      ok = ok && (tmax[r] <= m_run[r] + 8.f);
    }
    if (!__all(ok ? 1 : 0)) {
#pragma unroll
      for (int r = 0; r < 16; ++r) {
        const float mn = fmaxf(m_run[r], tmax[r]);
        const float sc = (mn == m_run[r]) ? 1.f : __expf(m_run[r] - mn);
        m_run[r] = mn;
        l_run[r] *= sc;
#pragma unroll
        for (int dt = 0; dt < 4; ++dt) acc[dt][r] *= sc;
      }
    }
    float psv[16];
#pragma unroll
    for (int r = 0; r < 16; ++r)
      psv[r] = (sv[r] == -INFINITY) ? 0.f : __expf(sv[r] - m_run[r]);
#pragma unroll
    for (int r = 0; r < 16; ++r) l_run[r] += red32add(psv[r]);

    // ---- P -> LDS (per-wave region), then PV: 8 MFMA ----
#pragma unroll
    for (int r = 0; r < 16; ++r) {
      const int ql = (r & 3) + 8 * (r >> 2) + 4 * hi;
      PsL[w][ql * 40 + l32] = f2bf(psv[r]);
    }
    asm volatile("s_waitcnt lgkmcnt(0)" ::: "memory");
    __builtin_amdgcn_sched_barrier(0);

    const s16x8 pf0 = *(const s16x8*)&PsL[w][l32 * 40 + hi * 8];
    const s16x8 pf1 = *(const s16x8*)&PsL[w][l32 * 40 + 16 + hi * 8];
    __builtin_amdgcn_s_setprio(1);
#pragma unroll
    for (int dt = 0; dt < 4; ++dt) {
      const s16x8 vf0 = *(const s16x8*)&VtL[bf][dt * 1024 + hi * 256 + l32 * 8];
      const s16x8 vf1 = *(const s16x8*)&VtL[bf][dt * 1024 + (2 + hi) * 256 + l32 * 8];
      acc[dt] = __builtin_amdgcn_mfma_f32_32x32x16_bf16(pf0, vf0, acc[dt], 0, 0, 0);
      acc[dt] = __builtin_amdgcn_mfma_f32_32x32x16_bf16(pf1, vf1, acc[dt], 0, 0, 0);
    }
    __builtin_amdgcn_s_setprio(0);
  }

  // ---- epilogue ----
  float inv[16];
#pragma unroll
  for (int r = 0; r < 16; ++r) inv[r] = (l_run[r] > 0.f) ? 1.f / l_run[r] : 0.f;

#pragma unroll
  for (int dt = 0; dt < 4; ++dt) {
#pragma unroll
    for (int r = 0; r < 16; ++r) {
      const int q = q0 + (r & 3) + 8 * (r >> 2) + 4 * hi;
      const float o = acc[dt][r] * inv[r];
      if (dt == 0) {
        Hres[((size_t)(b * 1024 + q)) * 512 + h * 32 + l32] = o;
      } else {
        Vres[(((size_t)(b * 1024 + q)) * 3 + (dt - 1)) * 512 + h * 32 + l32] = o;
      }
    }
  }
}

// ---------------------------------------------------------------------------
extern "C" void kernel_launch(void* const* d_in, const int* in_sizes, int n_in,
                              void* d_out, int out_size, void* d_ws, size_t ws_size,
                              hipStream_t stream)
{
  const float* Hp  = (const float*)d_in[0];
  const float* Vp  = (const float*)d_in[1];
  const float* Db  = (const float*)d_in[2];
  const float* rbf = (const float*)d_in[3];
  const int*   Hm  = (const int*)d_in[4];
  const float* Wq  = (const float*)d_in[5];
  const float* bq  = (const float*)d_in[6];
  const float* Wk  = (const float*)d_in[7];
  const float* bk  = (const float*)d_in[8];
  const float* Wv  = (const float*)d_in[9];
  const float* bv  = (const float*)d_in[10];
  const float* Wvv = (const float*)d_in[11];
  const float* Wo  = (const float*)d_in[12];
  const float* bo  = (const float*)d_in[13];
  const float* Wvo = (const float*)d_in[14];
  float* out = (float*)d_out;

  // ws (bytes): Qb 16M | Kb 16M | Vt 16M | Hres 8M | Vres 24M = 80MB
  if (ws_size < (size_t)83886080) return;
  unsigned short* Qb = (unsigned short*)d_ws;
  unsigned short* Kb = Qb + 8388608;
  unsigned short* Vt = Kb + 8388608;
  float* Hres = (float*)(Vt + 8388608);
  float* Vres = Hres + 2097152;

  const dim3 blk(256);

  gemm_mfma<<<dim3(32, 16), blk, 0, stream>>>(Hp, Wq, bq, Qb, 4096, 2048, 512, 3);
  gemm_mfma<<<dim3(32, 16), blk, 0, stream>>>(Hp, Wk, bk, Kb, 4096, 2048, 512, 3);
  gemm_mfma<<<dim3(4, 32),  blk, 0, stream>>>(Wv, Hp, bv, Vt, 512, 4096, 512, 4);
  gemm_mfma<<<dim3(4, 96),  blk, 0, stream>>>(Wvv, Vp, nullptr, Vt, 512, 12288, 512, 5);

  attn_mfma<<<dim3(8, 64), blk, 0, stream>>>(Qb, Kb, Vt, rbf, Db, Hm, Hres, Vres);

  gemm_mfma<<<dim3(32, 4), blk, 0, stream>>>(Hres, Wo, bo, out, 4096, 512, 512, 0);
  gemm_mfma<<<dim3(96, 4), blk, 0, stream>>>(Vres, Wvo, nullptr, out + 2097152, 12288, 512, 512, 0);
}

// Round 13
// 290.193 us; speedup vs baseline: 1.4595x; 1.0282x over previous
//
#include <hip/hip_runtime.h>
#include <cmath>

#define FACTOR 0.08838834764831845f

typedef short s16x8 __attribute__((ext_vector_type(8)));
typedef float f32x4 __attribute__((ext_vector_type(4)));
typedef float f32x16 __attribute__((ext_vector_type(16)));
typedef unsigned int u32;

#define KEEP_LOADS() do { asm volatile("" ::: "memory"); __builtin_amdgcn_sched_barrier(0); } while (0)

__device__ __forceinline__ unsigned short f2bf(float x) {
  unsigned int u = __float_as_uint(x);
  u += 0x7FFFu + ((u >> 16) & 1u);
  return (unsigned short)(u >> 16);
}

__device__ __forceinline__ s16x8 pack8(float4 a, float4 b) {
  s16x8 r;
  r[0] = (short)f2bf(a.x); r[1] = (short)f2bf(a.y);
  r[2] = (short)f2bf(a.z); r[3] = (short)f2bf(a.w);
  r[4] = (short)f2bf(b.x); r[5] = (short)f2bf(b.y);
  r[6] = (short)f2bf(b.z); r[7] = (short)f2bf(b.w);
  return r;
}

__device__ __forceinline__ void gload_lds16(const void* g, void* l) {
  __builtin_amdgcn_global_load_lds(
      (const __attribute__((address_space(1))) u32*)g,
      (__attribute__((address_space(3))) u32*)l, 16, 0, 0);
}

// ---- 32-lane reductions: 4 DPP (VALU) + 1 ds_swizzle(xor16) ----
template <int CTRL>
__device__ __forceinline__ float dppmax(float x) {
  int y = __builtin_amdgcn_mov_dpp(__float_as_int(x), CTRL, 0xf, 0xf, false);
  return fmaxf(x, __int_as_float(y));
}
template <int CTRL>
__device__ __forceinline__ float dppadd(float x) {
  int y = __builtin_amdgcn_mov_dpp(__float_as_int(x), CTRL, 0xf, 0xf, false);
  return x + __int_as_float(y);
}
__device__ __forceinline__ float swz16(float x) {
  return __int_as_float(__builtin_amdgcn_ds_swizzle(__float_as_int(x), 0x401F));
}
__device__ __forceinline__ float red32max(float x) {
  x = dppmax<0xB1>(x);
  x = dppmax<0x4E>(x);
  x = dppmax<0x141>(x);
  x = dppmax<0x140>(x);
  return fmaxf(x, swz16(x));
}
__device__ __forceinline__ float red32add(float x) {
  x = dppadd<0xB1>(x);
  x = dppadd<0x4E>(x);
  x = dppadd<0x141>(x);
  x = dppadd<0x140>(x);
  return x + swz16(x);
}

// ---------------------------------------------------------------------------
// MFMA GEMM (unchanged, R12-passing).
// mode 0: f32 C | mode 3: bf16 C | mode 4/5: Vt scatters (5 = fused V transpose)
// ---------------------------------------------------------------------------
__global__ __launch_bounds__(256) void gemm_mfma(
    const float* __restrict__ A, const float* __restrict__ B,
    const float* __restrict__ bias, void* __restrict__ C,
    int M, int N, int K, int mode)
{
  __shared__ unsigned short As[128 * 72];
  __shared__ unsigned short Bs[128 * 72];

  const int tid = threadIdx.x;
  const int w = tid >> 6, lane = tid & 63;
  const int l16 = lane & 15, lg = lane >> 4;
  const int wm = w >> 1, wn = w & 1;
  const int m0 = blockIdx.x * 128;
  const int n0 = blockIdx.y * 128;

  const int sr = tid >> 3;
  const int sc = (tid & 7) * 8;

  float4 ar[4][2], br[4][2];

  auto issue = [&](int k0) {
#pragma unroll
    for (int i = 0; i < 4; ++i) {
      const int rr = i * 32 + sr;
      const float* ap = A + (size_t)(m0 + rr) * K + k0 + sc;
      ar[i][0] = *(const float4*)ap;
      ar[i][1] = *(const float4*)(ap + 4);
      const float* bp;
      if (mode == 5) {
        const int t = n0 + rr;
        const int q3 = t >> 10, n = t & 1023;
        const int bb = q3 / 3, cd = q3 - 3 * bb;
        bp = B + (((size_t)(bb * 1024 + n)) * 3 + cd) * 512 + k0 + sc;
      } else {
        bp = B + (size_t)(n0 + rr) * K + k0 + sc;
      }
      br[i][0] = *(const float4*)bp;
      br[i][1] = *(const float4*)(bp + 4);
    }
  };

  f32x4 acc[4][4];
#pragma unroll
  for (int mt = 0; mt < 4; ++mt)
#pragma unroll
    for (int nt = 0; nt < 4; ++nt)
#pragma unroll
      for (int r = 0; r < 4; ++r) acc[mt][nt][r] = 0.f;

  issue(0);

#pragma unroll 1
  for (int k0 = 0; k0 < K; k0 += 64) {
    __builtin_amdgcn_s_barrier();
#pragma unroll
    for (int i = 0; i < 4; ++i) {
      const int rr = i * 32 + sr;
      *(s16x8*)&As[rr * 72 + sc] = pack8(ar[i][0], ar[i][1]);
      *(s16x8*)&Bs[rr * 72 + sc] = pack8(br[i][0], br[i][1]);
    }
    asm volatile("s_waitcnt lgkmcnt(0)" ::: "memory");
    __builtin_amdgcn_s_barrier();
    if (k0 + 64 < K) issue(k0 + 64);
    KEEP_LOADS();

#pragma unroll
    for (int ks = 0; ks < 2; ++ks) {
      s16x8 af[4], bf[4];
#pragma unroll
      for (int mt = 0; mt < 4; ++mt)
        af[mt] = *(const s16x8*)&As[(wm * 64 + mt * 16 + l16) * 72 + ks * 32 + lg * 8];
#pragma unroll
      for (int nt = 0; nt < 4; ++nt)
        bf[nt] = *(const s16x8*)&Bs[(wn * 64 + nt * 16 + l16) * 72 + ks * 32 + lg * 8];
#pragma unroll
      for (int mt = 0; mt < 4; ++mt)
#pragma unroll
        for (int nt = 0; nt < 4; ++nt)
          acc[mt][nt] = __builtin_amdgcn_mfma_f32_16x16x32_bf16(af[mt], bf[nt], acc[mt][nt], 0, 0, 0);
    }
  }

  const int rbase = m0 + wm * 64;
  const int cbase = n0 + wn * 64;

  if (mode == 0 || mode == 3) {
#pragma unroll
    for (int nt = 0; nt < 4; ++nt) {
      const int c = cbase + nt * 16 + l16;
      const float bb = bias ? bias[c] : 0.f;
#pragma unroll
      for (int mt = 0; mt < 4; ++mt) {
#pragma unroll
        for (int r = 0; r < 4; ++r) {
          const int row = rbase + mt * 16 + lg * 4 + r;
          const float v = acc[mt][nt][r] + bb;
          if (mode == 0) ((float*)C)[(size_t)row * N + c] = v;
          else           ((unsigned short*)C)[(size_t)row * N + c] = f2bf(v);
        }
      }
    }
  } else {
    unsigned short* Cb = (unsigned short*)C;
#pragma unroll
    for (int mt = 0; mt < 4; ++mt) {
#pragma unroll
      for (int r = 0; r < 4; ++r) {
        const int ch = rbase + mt * 16 + lg * 4 + r;
        const float bb = bias ? bias[ch] : 0.f;
        const int h = ch >> 5, dq = ch & 31;
#pragma unroll
        for (int nt = 0; nt < 4; ++nt) {
          const int t = cbase + nt * 16 + l16;
          size_t off;
          if (mode == 4) {
            const int b = t >> 10, n = t & 1023;
            off = (((size_t)(b * 16 + h)) * 128 + dq) * 1024 + n;
          } else {
            const int q3 = t >> 10, n = t & 1023;
            const int b = q3 / 3, cd = q3 - 3 * b;
            off = (((size_t)(b * 16 + h)) * 128 + 32 + cd * 32 + dq) * 1024 + n;
          }
          Cb[off] = f2bf(acc[mt][nt][r] + bb);
        }
      }
    }
  }
}

// ---------------------------------------------------------------------------
// Flash attention, 32x32x16 MFMA, 32 q/wave, q-tile 128/block, m-tile 32.
// K/V: double-buffered DMA, slab-transposed placement (0 bank conflicts).
// Bias: single-buffered DMA into per-wave LDS slab, prefetched one tile ahead
// (issued right after sv(t) consume -> ~1500cy hide window, no VGPR cost).
// Softmax: DPP reductions. Defer-max THR=8.
// ---------------------------------------------------------------------------
__global__ __launch_bounds__(256, 2) void attn_mfma(
    const unsigned short* __restrict__ Qg, const unsigned short* __restrict__ Kg,
    const unsigned short* __restrict__ Vtg, const float* __restrict__ rbf,
    const float* __restrict__ Dm, const int* __restrict__ msk,
    float* __restrict__ Hres, float* __restrict__ Vres)
{
  __shared__ unsigned short KsL[2][4096];   // slabs: ko(16) x m(32) x 16B
  __shared__ unsigned short VtL[2][4096];   // dt(4) x o(4) x d'(32) x 16B
  __shared__ unsigned short PsL[4][32 * 40];
  __shared__ int   MsL[1024];
  __shared__ float RbL[128 * 32];           // 16KB: [q_block 128][m 32]
  __shared__ float DbL[128 * 32];           // 16KB

  const int tid  = threadIdx.x;
  const int w    = tid >> 6;
  const int lane = tid & 63;
  const int l32  = lane & 31;
  const int hi   = lane >> 5;

  const int bh = blockIdx.y;
  const int b  = bh >> 4;
  const int h  = bh & 15;
  const int q0 = blockIdx.x * 128 + w * 32;

  // ---- Q fragments: 8 k-steps x 8 bf16 ----
  s16x8 qf[8];
  {
    const unsigned short* qp = Qg + ((size_t)(b * 1024 + q0 + l32)) * 2048 + h * 128 + hi * 8;
#pragma unroll
    for (int ks = 0; ks < 8; ++ks) qf[ks] = *(const s16x8*)(qp + ks * 16);
  }

  f32x16 acc[4];
  float m_run[16], l_run[16];
#pragma unroll
  for (int dt = 0; dt < 4; ++dt)
#pragma unroll
    for (int r = 0; r < 16; ++r) acc[dt][r] = 0.f;
#pragma unroll
  for (int r = 0; r < 16; ++r) { m_run[r] = -INFINITY; l_run[r] = 0.f; }

  // ---- DMA one tile of K/V: 4 instr/wave, slab-transposed placement ----
  auto issue_kv = [&](int t, int bf) {
    const int m0 = t * 32;
#pragma unroll
    for (int jj = 0; jj < 2; ++jj) {
      const int i = w * 2 + jj;            // 0..7
      gload_lds16(Kg + ((size_t)(b * 1024 + m0 + l32)) * 2048 + h * 128 + (2 * i + hi) * 8,
                  &KsL[bf][i * 512]);
      gload_lds16(Vtg + ((size_t)(bh * 128 + (i >> 1) * 32 + l32)) * 1024 + m0 + ((i & 1) * 2 + hi) * 8,
                  &VtL[bf][i * 512]);
    }
  };

  // ---- DMA one tile of bias into this wave's private slab: 8 instr/wave ----
  // wave region = [q0w .. q0w+32) x [m0 .. m0+32); 4 instrs per array,
  // instr i: rows i*8+(lane>>3), chunk lane&7 (16B), dest linear.
  auto issue_bias = [&](int t) {
    const int m0 = t * 32;
#pragma unroll
    for (int i = 0; i < 4; ++i) {
      const int qq = q0 + i * 8 + (lane >> 3);
      const int ch = (lane & 7) * 4;
      gload_lds16(rbf + ((size_t)bh * 1024 + qq) * 1024 + m0 + ch, &RbL[w * 1024 + i * 256]);
      gload_lds16(Dm  + ((size_t)b  * 1024 + qq) * 1024 + m0 + ch, &DbL[w * 1024 + i * 256]);
    }
  };

  // ---- prologue: mask (whole b) + tile 0 K/V + tile 0 bias ----
  gload_lds16(msk + b * 1024 + w * 256 + lane * 4, &MsL[w * 256]);
  issue_kv(0, 0);
  issue_bias(0);

#pragma unroll 1
  for (int t = 0; t < 32; ++t) {
    const int bf = t & 1;
    const int m0 = t * 32;

    asm volatile("s_waitcnt vmcnt(0)" ::: "memory");   // this wave's DMAs landed
    __builtin_amdgcn_s_barrier();                      // all waves' K/V landed

    if (t < 31) issue_kv(t + 1, bf ^ 1);
    __builtin_amdgcn_sched_barrier(0);

    // ---- QK: 8 MFMA 32x32x16 ----
    f32x16 sf;
#pragma unroll
    for (int r = 0; r < 16; ++r) sf[r] = 0.f;
    __builtin_amdgcn_s_setprio(1);
#pragma unroll
    for (int ks = 0; ks < 8; ++ks) {
      const s16x8 kf = *(const s16x8*)&KsL[bf][(ks * 2 + hi) * 256 + l32 * 8];
      sf = __builtin_amdgcn_mfma_f32_32x32x16_bf16(qf[ks], kf, sf, 0, 0, 0);
    }
    __builtin_amdgcn_s_setprio(0);

    // ---- bias from LDS (conflict-free b32) + mask ----
    const bool on = MsL[m0 + l32] != 0;
    float sv[16];
#pragma unroll
    for (int r = 0; r < 16; ++r) {
      const int ql = (r & 3) + 8 * (r >> 2) + 4 * hi;
      const float bb = RbL[w * 1024 + ql * 32 + l32] + DbL[w * 1024 + ql * 32 + l32];
      sv[r] = on ? fmaf(sf[r], FACTOR, bb) : -INFINITY;
    }
    // bias(t) fully consumed (lgkm waits forced above) -> stage bias(t+1)
    if (t < 31) issue_bias(t + 1);
    __builtin_amdgcn_sched_barrier(0);

    // ---- online softmax (16 rows/lane, DPP reductions over 32 lanes) ----
    float tmax[16];
    bool ok = true;
#pragma unroll
    for (int r = 0; r < 16; ++r) {
      tmax[r] = red32max(sv[r]);
      ok = ok && (tmax[r] <= m_run[r] + 8.f);
    }
    if (!__all(ok ? 1 : 0)) {
#pragma unroll
      for (int r = 0; r < 16; ++r) {
        const float mn = fmaxf(m_run[r], tmax[r]);
        const float sc = (mn == m_run[r]) ? 1.f : __expf(m_run[r] - mn);
        m_run[r] = mn;
        l_run[r] *= sc;
#pragma unroll
        for (int dt = 0; dt < 4; ++dt) acc[dt][r] *= sc;
      }
    }
    float psv[16];
#pragma unroll
    for (int r = 0; r < 16; ++r)
      psv[r] = (sv[r] == -INFINITY) ? 0.f : __expf(sv[r] - m_run[r]);
#pragma unroll
    for (int r = 0; r < 16; ++r) l_run[r] += red32add(psv[r]);

    // ---- P -> LDS (per-wave region), then PV: 8 MFMA ----
#pragma unroll
    for (int r = 0; r < 16; ++r) {
      const int ql = (r & 3) + 8 * (r >> 2) + 4 * hi;
      PsL[w][ql * 40 + l32] = f2bf(psv[r]);
    }
    asm volatile("s_waitcnt lgkmcnt(0)" ::: "memory");
    __builtin_amdgcn_sched_barrier(0);

    const s16x8 pf0 = *(const s16x8*)&PsL[w][l32 * 40 + hi * 8];
    const s16x8 pf1 = *(const s16x8*)&PsL[w][l32 * 40 + 16 + hi * 8];
    __builtin_amdgcn_s_setprio(1);
#pragma unroll
    for (int dt = 0; dt < 4; ++dt) {
      const s16x8 vf0 = *(const s16x8*)&VtL[bf][dt * 1024 + hi * 256 + l32 * 8];
      const s16x8 vf1 = *(const s16x8*)&VtL[bf][dt * 1024 + (2 + hi) * 256 + l32 * 8];
      acc[dt] = __builtin_amdgcn_mfma_f32_32x32x16_bf16(pf0, vf0, acc[dt], 0, 0, 0);
      acc[dt] = __builtin_amdgcn_mfma_f32_32x32x16_bf16(pf1, vf1, acc[dt], 0, 0, 0);
    }
    __builtin_amdgcn_s_setprio(0);
  }

  // ---- epilogue ----
  float inv[16];
#pragma unroll
  for (int r = 0; r < 16; ++r) inv[r] = (l_run[r] > 0.f) ? 1.f / l_run[r] : 0.f;

#pragma unroll
  for (int dt = 0; dt < 4; ++dt) {
#pragma unroll
    for (int r = 0; r < 16; ++r) {
      const int q = q0 + (r & 3) + 8 * (r >> 2) + 4 * hi;
      const float o = acc[dt][r] * inv[r];
      if (dt == 0) {
        Hres[((size_t)(b * 1024 + q)) * 512 + h * 32 + l32] = o;
      } else {
        Vres[(((size_t)(b * 1024 + q)) * 3 + (dt - 1)) * 512 + h * 32 + l32] = o;
      }
    }
  }
}

// ---------------------------------------------------------------------------
extern "C" void kernel_launch(void* const* d_in, const int* in_sizes, int n_in,
                              void* d_out, int out_size, void* d_ws, size_t ws_size,
                              hipStream_t stream)
{
  const float* Hp  = (const float*)d_in[0];
  const float* Vp  = (const float*)d_in[1];
  const float* Db  = (const float*)d_in[2];
  const float* rbf = (const float*)d_in[3];
  const int*   Hm  = (const int*)d_in[4];
  const float* Wq  = (const float*)d_in[5];
  const float* bq  = (const float*)d_in[6];
  const float* Wk  = (const float*)d_in[7];
  const float* bk  = (const float*)d_in[8];
  const float* Wv  = (const float*)d_in[9];
  const float* bv  = (const float*)d_in[10];
  const float* Wvv = (const float*)d_in[11];
  const float* Wo  = (const float*)d_in[12];
  const float* bo  = (const float*)d_in[13];
  const float* Wvo = (const float*)d_in[14];
  float* out = (float*)d_out;

  // ws (bytes): Qb 16M | Kb 16M | Vt 16M | Hres 8M | Vres 24M = 80MB
  if (ws_size < (size_t)83886080) return;
  unsigned short* Qb = (unsigned short*)d_ws;
  unsigned short* Kb = Qb + 8388608;
  unsigned short* Vt = Kb + 8388608;
  float* Hres = (float*)(Vt + 8388608);
  float* Vres = Hres + 2097152;

  const dim3 blk(256);

  gemm_mfma<<<dim3(32, 16), blk, 0, stream>>>(Hp, Wq, bq, Qb, 4096, 2048, 512, 3);
  gemm_mfma<<<dim3(32, 16), blk, 0, stream>>>(Hp, Wk, bk, Kb, 4096, 2048, 512, 3);
  gemm_mfma<<<dim3(4, 32),  blk, 0, stream>>>(Wv, Hp, bv, Vt, 512, 4096, 512, 4);
  gemm_mfma<<<dim3(4, 96),  blk, 0, stream>>>(Wvv, Vp, nullptr, Vt, 512, 12288, 512, 5);

  attn_mfma<<<dim3(8, 64), blk, 0, stream>>>(Qb, Kb, Vt, rbf, Db, Hm, Hres, Vres);

  gemm_mfma<<<dim3(32, 4), blk, 0, stream>>>(Hres, Wo, bo, out, 4096, 512, 512, 0);
  gemm_mfma<<<dim3(96, 4), blk, 0, stream>>>(Vres, Wvo, nullptr, out + 2097152, 12288, 512, 512, 0);
}

// Round 16
// 275.220 us; speedup vs baseline: 1.5389x; 1.0544x over previous
//
#include <hip/hip_runtime.h>
#include <cmath>

#define FACTOR 0.08838834764831845f

typedef short s16x8 __attribute__((ext_vector_type(8)));
typedef float f32x4 __attribute__((ext_vector_type(4)));
typedef float f32x16 __attribute__((ext_vector_type(16)));
typedef unsigned int u32;

#define KEEP_LOADS() do { asm volatile("" ::: "memory"); __builtin_amdgcn_sched_barrier(0); } while (0)

__device__ __forceinline__ unsigned short f2bf(float x) {
  unsigned int u = __float_as_uint(x);
  u += 0x7FFFu + ((u >> 16) & 1u);
  return (unsigned short)(u >> 16);
}

__device__ __forceinline__ s16x8 pack8(float4 a, float4 b) {
  s16x8 r;
  r[0] = (short)f2bf(a.x); r[1] = (short)f2bf(a.y);
  r[2] = (short)f2bf(a.z); r[3] = (short)f2bf(a.w);
  r[4] = (short)f2bf(b.x); r[5] = (short)f2bf(b.y);
  r[6] = (short)f2bf(b.z); r[7] = (short)f2bf(b.w);
  return r;
}

__device__ __forceinline__ void gload_lds16(const void* g, void* l) {
  __builtin_amdgcn_global_load_lds(
      (const __attribute__((address_space(1))) u32*)g,
      (__attribute__((address_space(3))) u32*)l, 16, 0, 0);
}

// ---------------------------------------------------------------------------
// MFMA GEMM (R13-passing version: f2bf pack8, raw-barrier pipeline).
// mode 0: f32 C | mode 3: bf16 C | mode 4/5: Vt scatters (5 = fused V transpose)
// ---------------------------------------------------------------------------
__global__ __launch_bounds__(256) void gemm_mfma(
    const float* __restrict__ A, const float* __restrict__ B,
    const float* __restrict__ bias, void* __restrict__ C,
    int M, int N, int K, int mode)
{
  __shared__ unsigned short As[128 * 72];
  __shared__ unsigned short Bs[128 * 72];

  const int tid = threadIdx.x;
  const int w = tid >> 6, lane = tid & 63;
  const int l16 = lane & 15, lg = lane >> 4;
  const int wm = w >> 1, wn = w & 1;
  const int m0 = blockIdx.x * 128;
  const int n0 = blockIdx.y * 128;

  const int sr = tid >> 3;
  const int sc = (tid & 7) * 8;

  float4 ar[4][2], br[4][2];

  auto issue = [&](int k0) {
#pragma unroll
    for (int i = 0; i < 4; ++i) {
      const int rr = i * 32 + sr;
      const float* ap = A + (size_t)(m0 + rr) * K + k0 + sc;
      ar[i][0] = *(const float4*)ap;
      ar[i][1] = *(const float4*)(ap + 4);
      const float* bp;
      if (mode == 5) {
        const int t = n0 + rr;
        const int q3 = t >> 10, n = t & 1023;
        const int bb = q3 / 3, cd = q3 - 3 * bb;
        bp = B + (((size_t)(bb * 1024 + n)) * 3 + cd) * 512 + k0 + sc;
      } else {
        bp = B + (size_t)(n0 + rr) * K + k0 + sc;
      }
      br[i][0] = *(const float4*)bp;
      br[i][1] = *(const float4*)(bp + 4);
    }
  };

  f32x4 acc[4][4];
#pragma unroll
  for (int mt = 0; mt < 4; ++mt)
#pragma unroll
    for (int nt = 0; nt < 4; ++nt)
#pragma unroll
      for (int r = 0; r < 4; ++r) acc[mt][nt][r] = 0.f;

  issue(0);

#pragma unroll 1
  for (int k0 = 0; k0 < K; k0 += 64) {
    __builtin_amdgcn_s_barrier();
#pragma unroll
    for (int i = 0; i < 4; ++i) {
      const int rr = i * 32 + sr;
      *(s16x8*)&As[rr * 72 + sc] = pack8(ar[i][0], ar[i][1]);
      *(s16x8*)&Bs[rr * 72 + sc] = pack8(br[i][0], br[i][1]);
    }
    asm volatile("s_waitcnt lgkmcnt(0)" ::: "memory");
    __builtin_amdgcn_s_barrier();
    if (k0 + 64 < K) issue(k0 + 64);
    KEEP_LOADS();

#pragma unroll
    for (int ks = 0; ks < 2; ++ks) {
      s16x8 af[4], bf[4];
#pragma unroll
      for (int mt = 0; mt < 4; ++mt)
        af[mt] = *(const s16x8*)&As[(wm * 64 + mt * 16 + l16) * 72 + ks * 32 + lg * 8];
#pragma unroll
      for (int nt = 0; nt < 4; ++nt)
        bf[nt] = *(const s16x8*)&Bs[(wn * 64 + nt * 16 + l16) * 72 + ks * 32 + lg * 8];
#pragma unroll
      for (int mt = 0; mt < 4; ++mt)
#pragma unroll
        for (int nt = 0; nt < 4; ++nt)
          acc[mt][nt] = __builtin_amdgcn_mfma_f32_16x16x32_bf16(af[mt], bf[nt], acc[mt][nt], 0, 0, 0);
    }
  }

  const int rbase = m0 + wm * 64;
  const int cbase = n0 + wn * 64;

  if (mode == 0 || mode == 3) {
#pragma unroll
    for (int nt = 0; nt < 4; ++nt) {
      const int c = cbase + nt * 16 + l16;
      const float bb = bias ? bias[c] : 0.f;
#pragma unroll
      for (int mt = 0; mt < 4; ++mt) {
#pragma unroll
        for (int r = 0; r < 4; ++r) {
          const int row = rbase + mt * 16 + lg * 4 + r;
          const float v = acc[mt][nt][r] + bb;
          if (mode == 0) ((float*)C)[(size_t)row * N + c] = v;
          else           ((unsigned short*)C)[(size_t)row * N + c] = f2bf(v);
        }
      }
    }
  } else {
    unsigned short* Cb = (unsigned short*)C;
#pragma unroll
    for (int mt = 0; mt < 4; ++mt) {
#pragma unroll
      for (int r = 0; r < 4; ++r) {
        const int ch = rbase + mt * 16 + lg * 4 + r;
        const float bb = bias ? bias[ch] : 0.f;
        const int h = ch >> 5, dq = ch & 31;
#pragma unroll
        for (int nt = 0; nt < 4; ++nt) {
          const int t = cbase + nt * 16 + l16;
          size_t off;
          if (mode == 4) {
            const int b = t >> 10, n = t & 1023;
            off = (((size_t)(b * 16 + h)) * 128 + dq) * 1024 + n;
          } else {
            const int q3 = t >> 10, n = t & 1023;
            const int b = q3 / 3, cd = q3 - 3 * b;
            off = (((size_t)(b * 16 + h)) * 128 + 32 + cd * 32 + dq) * 1024 + n;
          }
          Cb[off] = f2bf(acc[mt][nt][r] + bb);
        }
      }
    }
  }
}

// ---------------------------------------------------------------------------
// Flash attention. QK + bias as R13 (verified). S transposed via per-wave
// pitch-18 LDS slab -> lane-local softmax (lane = q); cross-half combines via
// __shfl_xor(x,32). P packed (f2bf) into the SAME slab, read back as b128
// B-fragments. PV operand-swapped mfma(A=V, B=P) -> acc cols=q.
// Only primitives exercised by prior passing rounds.
// ---------------------------------------------------------------------------
__global__ __launch_bounds__(256, 2) void attn_mfma(
    const unsigned short* __restrict__ Qg, const unsigned short* __restrict__ Kg,
    const unsigned short* __restrict__ Vtg, const float* __restrict__ rbf,
    const float* __restrict__ Dm, const int* __restrict__ msk,
    float* __restrict__ Hres, float* __restrict__ Vres)
{
  __shared__ unsigned short KsL[2][4096];   // slabs: ko(16) x m(32) x 16B
  __shared__ unsigned short VtL[2][4096];   // dt(4) x o(4) x d'(32) x 16B
  __shared__ int   MsL[1024];
  __shared__ float RbL[128 * 32];           // [q_block 128][m 32]
  __shared__ float DbL[128 * 32];
  __shared__ float SsL[4][32 * 18];         // per-wave slab: S-transpose, then P

  const int tid  = threadIdx.x;
  const int w    = tid >> 6;
  const int lane = tid & 63;
  const int l32  = lane & 31;
  const int hi   = lane >> 5;

  const int bh = blockIdx.y;
  const int b  = bh >> 4;
  const int h  = bh & 15;
  const int q0 = blockIdx.x * 128 + w * 32;

  // ---- Q fragments: 8 k-steps x 8 bf16 ----
  s16x8 qf[8];
  {
    const unsigned short* qp = Qg + ((size_t)(b * 1024 + q0 + l32)) * 2048 + h * 128 + hi * 8;
#pragma unroll
    for (int ks = 0; ks < 8; ++ks) qf[ks] = *(const s16x8*)(qp + ks * 16);
  }

  f32x16 acc[4];        // O[q = l32][d = dt*32 + (r&3)+8*(r>>2)+4*hi]
  float m_run = -INFINITY, l_run = 0.f;   // per-lane (q = l32, m-half = hi)
#pragma unroll
  for (int dt = 0; dt < 4; ++dt)
#pragma unroll
    for (int r = 0; r < 16; ++r) acc[dt][r] = 0.f;

  // ---- DMA one tile of K/V: 4 instr/wave, slab-transposed placement ----
  auto issue_kv = [&](int t, int bf) {
    const int m0 = t * 32;
#pragma unroll
    for (int jj = 0; jj < 2; ++jj) {
      const int i = w * 2 + jj;
      gload_lds16(Kg + ((size_t)(b * 1024 + m0 + l32)) * 2048 + h * 128 + (2 * i + hi) * 8,
                  &KsL[bf][i * 512]);
      gload_lds16(Vtg + ((size_t)(bh * 128 + (i >> 1) * 32 + l32)) * 1024 + m0 + ((i & 1) * 2 + hi) * 8,
                  &VtL[bf][i * 512]);
    }
  };

  // ---- DMA one tile of bias into this wave's private slab ----
  auto issue_bias = [&](int t) {
    const int m0 = t * 32;
#pragma unroll
    for (int i = 0; i < 4; ++i) {
      const int qq = q0 + i * 8 + (lane >> 3);
      const int ch = (lane & 7) * 4;
      gload_lds16(rbf + ((size_t)bh * 1024 + qq) * 1024 + m0 + ch, &RbL[w * 1024 + i * 256]);
      gload_lds16(Dm  + ((size_t)b  * 1024 + qq) * 1024 + m0 + ch, &DbL[w * 1024 + i * 256]);
    }
  };

  gload_lds16(msk + b * 1024 + w * 256 + lane * 4, &MsL[w * 256]);
  issue_kv(0, 0);
  issue_bias(0);

#pragma unroll 1
  for (int t = 0; t < 32; ++t) {
    const int bf = t & 1;
    const int m0 = t * 32;

    asm volatile("s_waitcnt vmcnt(0)" ::: "memory");
    __builtin_amdgcn_s_barrier();

    if (t < 31) issue_kv(t + 1, bf ^ 1);
    __builtin_amdgcn_sched_barrier(0);

    // ---- QK: 8 MFMA 32x32x16 (sf: rows q in regs, col m = l32) ----
    f32x16 sf;
#pragma unroll
    for (int r = 0; r < 16; ++r) sf[r] = 0.f;
    __builtin_amdgcn_s_setprio(1);
#pragma unroll
    for (int ks = 0; ks < 8; ++ks) {
      const s16x8 kf = *(const s16x8*)&KsL[bf][(ks * 2 + hi) * 256 + l32 * 8];
      sf = __builtin_amdgcn_mfma_f32_32x32x16_bf16(qf[ks], kf, sf, 0, 0, 0);
    }
    __builtin_amdgcn_s_setprio(0);

    // ---- bias from LDS (conflict-free) + mask ----
    const bool on = MsL[m0 + l32] != 0;
    float sv[16];
#pragma unroll
    for (int r = 0; r < 16; ++r) {
      const int ql = (r & 3) + 8 * (r >> 2) + 4 * hi;
      const float bb = RbL[w * 1024 + ql * 32 + l32] + DbL[w * 1024 + ql * 32 + l32];
      sv[r] = on ? fmaf(sf[r], FACTOR, bb) : -INFINITY;
    }
    // bias(t) fully consumed -> stage bias(t+1)
    asm volatile("s_waitcnt lgkmcnt(0)" ::: "memory");
    __builtin_amdgcn_sched_barrier(0);
    if (t < 31) issue_bias(t + 1);
    __builtin_amdgcn_sched_barrier(0);

    // ---- transpose S through per-wave slab (2 phases, pitch 18) ----
    float s[16];
    // phase 0: m 0..15
    if (l32 < 16) {
#pragma unroll
      for (int r = 0; r < 16; ++r) {
        const int ql = (r & 3) + 8 * (r >> 2) + 4 * hi;
        SsL[w][ql * 18 + l32] = sv[r];
      }
    }
    asm volatile("s_waitcnt lgkmcnt(0)" ::: "memory");
    __builtin_amdgcn_sched_barrier(0);
    if (hi == 0) {
#pragma unroll
      for (int j = 0; j < 16; ++j) s[j] = SsL[w][l32 * 18 + j];
    }
    __builtin_amdgcn_sched_barrier(0);
    // phase 1: m 16..31 (same-wave DS ordering protects WAR with phase-0 reads)
    if (l32 >= 16) {
#pragma unroll
      for (int r = 0; r < 16; ++r) {
        const int ql = (r & 3) + 8 * (r >> 2) + 4 * hi;
        SsL[w][ql * 18 + (l32 - 16)] = sv[r];
      }
    }
    asm volatile("s_waitcnt lgkmcnt(0)" ::: "memory");
    __builtin_amdgcn_sched_barrier(0);
    if (hi == 1) {
#pragma unroll
      for (int j = 0; j < 16; ++j) s[j] = SsL[w][l32 * 18 + j];
    }
    __builtin_amdgcn_sched_barrier(0);
    // now lane (q=l32, hi) holds S[q][m0 + hi*16 + j] in s[j]

    // ---- per-lane online softmax (cross-half via shfl_xor 32) ----
    float mx = s[0];
#pragma unroll
    for (int j = 1; j < 16; ++j) mx = fmaxf(mx, s[j]);
    const float tmax = fmaxf(mx, __shfl_xor(mx, 32));   // full 32-m max per q

    const bool ok = (tmax <= m_run + 8.f);
    if (!__all(ok ? 1 : 0)) {
      const float mn = fmaxf(m_run, tmax);
      const float sc = (mn == m_run) ? 1.f : __expf(m_run - mn);
      m_run = mn;
      l_run *= sc;
#pragma unroll
      for (int dt = 0; dt < 4; ++dt)
#pragma unroll
        for (int r = 0; r < 16; ++r) acc[dt][r] *= sc;
    }

    float psv[16];
    float rs = 0.f;
#pragma unroll
    for (int j = 0; j < 16; ++j) {
      psv[j] = (s[j] == -INFINITY) ? 0.f : __expf(s[j] - m_run);
      rs += psv[j];
    }
    l_run += rs;                                  // partial (own m-half)

    // ---- P -> LDS (same slab, bf16 [q][m] pitch 36 shorts), read b128 ----
    {
      u32* Pw = (u32*)&SsL[w][0];
#pragma unroll
      for (int j = 0; j < 8; ++j) {
        const u32 word = (u32)f2bf(psv[2 * j]) | ((u32)f2bf(psv[2 * j + 1]) << 16);
        Pw[l32 * 18 + hi * 8 + j] = word;        // P[q=l32][m = hi*16 + 2j, 2j+1]
      }
    }
    asm volatile("s_waitcnt lgkmcnt(0)" ::: "memory");
    __builtin_amdgcn_sched_barrier(0);

    const unsigned short* Pr = (const unsigned short*)&SsL[w][0];
    const s16x8 pf0 = *(const s16x8*)&Pr[l32 * 36 + hi * 8];        // k = hi*8+e
    const s16x8 pf1 = *(const s16x8*)&Pr[l32 * 36 + 16 + hi * 8];   // k = 16+hi*8+e

    // ---- PV: operand-swapped mfma(A=V, B=P) -> D cols = q ----
    __builtin_amdgcn_s_setprio(1);
#pragma unroll
    for (int dt = 0; dt < 4; ++dt) {
      const s16x8 vf0 = *(const s16x8*)&VtL[bf][dt * 1024 + hi * 256 + l32 * 8];
      const s16x8 vf1 = *(const s16x8*)&VtL[bf][dt * 1024 + (2 + hi) * 256 + l32 * 8];
      acc[dt] = __builtin_amdgcn_mfma_f32_32x32x16_bf16(vf0, pf0, acc[dt], 0, 0, 0);
      acc[dt] = __builtin_amdgcn_mfma_f32_32x32x16_bf16(vf1, pf1, acc[dt], 0, 0, 0);
    }
    __builtin_amdgcn_s_setprio(0);
  }

  // ---- epilogue: combine l halves, normalize, scattered-d writes ----
  const float lt = l_run + __shfl_xor(l_run, 32);
  const float inv = (lt > 0.f) ? 1.f / lt : 0.f;

  const int q = q0 + l32;
#pragma unroll
  for (int dt = 0; dt < 4; ++dt) {
#pragma unroll
    for (int r = 0; r < 16; ++r) {
      const int dloc = (r & 3) + 8 * (r >> 2) + 4 * hi;   // 0..31
      const float o = acc[dt][r] * inv;
      if (dt == 0) {
        Hres[((size_t)(b * 1024 + q)) * 512 + h * 32 + dloc] = o;
      } else {
        Vres[(((size_t)(b * 1024 + q)) * 3 + (dt - 1)) * 512 + h * 32 + dloc] = o;
      }
    }
  }
}

// ---------------------------------------------------------------------------
extern "C" void kernel_launch(void* const* d_in, const int* in_sizes, int n_in,
                              void* d_out, int out_size, void* d_ws, size_t ws_size,
                              hipStream_t stream)
{
  const float* Hp  = (const float*)d_in[0];
  const float* Vp  = (const float*)d_in[1];
  const float* Db  = (const float*)d_in[2];
  const float* rbf = (const float*)d_in[3];
  const int*   Hm  = (const int*)d_in[4];
  const float* Wq  = (const float*)d_in[5];
  const float* bq  = (const float*)d_in[6];
  const float* Wk  = (const float*)d_in[7];
  const float* bk  = (const float*)d_in[8];
  const float* Wv  = (const float*)d_in[9];
  const float* bv  = (const float*)d_in[10];
  const float* Wvv = (const float*)d_in[11];
  const float* Wo  = (const float*)d_in[12];
  const float* bo  = (const float*)d_in[13];
  const float* Wvo = (const float*)d_in[14];
  float* out = (float*)d_out;

  // ws (bytes): Qb 16M | Kb 16M | Vt 16M | Hres 8M | Vres 24M = 80MB
  if (ws_size < (size_t)83886080) return;
  unsigned short* Qb = (unsigned short*)d_ws;
  unsigned short* Kb = Qb + 8388608;
  unsigned short* Vt = Kb + 8388608;
  float* Hres = (float*)(Vt + 8388608);
  float* Vres = Hres + 2097152;

  const dim3 blk(256);

  gemm_mfma<<<dim3(32, 16), blk, 0, stream>>>(Hp, Wq, bq, Qb, 4096, 2048, 512, 3);
  gemm_mfma<<<dim3(32, 16), blk, 0, stream>>>(Hp, Wk, bk, Kb, 4096, 2048, 512, 3);
  gemm_mfma<<<dim3(4, 32),  blk, 0, stream>>>(Wv, Hp, bv, Vt, 512, 4096, 512, 4);
  gemm_mfma<<<dim3(4, 96),  blk, 0, stream>>>(Wvv, Vp, nullptr, Vt, 512, 12288, 512, 5);

  attn_mfma<<<dim3(8, 64), blk, 0, stream>>>(Qb, Kb, Vt, rbf, Db, Hm, Hres, Vres);

  gemm_mfma<<<dim3(32, 4), blk, 0, stream>>>(Hres, Wo, bo, out, 4096, 512, 512, 0);
  gemm_mfma<<<dim3(96, 4), blk, 0, stream>>>(Vres, Wvo, nullptr, out + 2097152, 12288, 512, 512, 0);
}